// Round 10
// baseline (350.710 us; speedup 1.0000x reference)
//
#include <hip/hip_runtime.h>

#define EN 5
#define KT 3
#define BB 16
#define CC 128
#define HWP 4096
#define DWC 256
#define NPAIR 48
#define EPSLN 1e-6f
#define HR 10
#define HPX 100
#define TSTRIDE 106

typedef float f32x4 __attribute__((ext_vector_type(4)));
typedef __bf16 bf16x8 __attribute__((ext_vector_type(8)));

__device__ __forceinline__ float bf2f(ushort u) {
  union { unsigned int u; float f; } v; v.u = ((unsigned int)u) << 16; return v.f;
}
__device__ __forceinline__ uint cvtpk(float lo, float hi) {
  uint r;
  asm("v_cvt_pk_bf16_f32 %0, %1, %2" : "=v"(r) : "v"(lo), "v"(hi));
  return r;
}
__device__ __forceinline__ ushort f2bf(float f) {
  union { float f; unsigned int u; } v; v.f = f;
  unsigned int r = v.u + 0x7FFFu + ((v.u >> 16) & 1u);
  return (ushort)(r >> 16);
}
__device__ __forceinline__ ushort f2bf1(float f) {
  return (ushort)(cvtpk(f, f) & 0xffffu);
}
__device__ __forceinline__ ushort4 pack4(float a, float b, float c, float d) {
  union { uint2 u; ushort4 s; } v;
  v.u.x = cvtpk(a, b);
  v.u.y = cvtpk(c, d);
  return v.s;
}

// ---------------- gate ----------------
__global__ void gate_kernel(const float* __restrict__ weights, float* __restrict__ gate_w,
                            int* __restrict__ pair_e, float* __restrict__ out_counts,
                            float* __restrict__ out_weights, float* __restrict__ mean_raw) {
  __shared__ int sel[NPAIR];
  int tid = threadIdx.x;
  if (tid < BB) {
    float w[EN];
    for (int e = 0; e < EN; e++) w[e] = weights[tid * EN + e];
    int ch[KT]; float cv[KT]; float sum = 0.f;
    for (int j = 0; j < KT; j++) {
      int best = -1; float bv = -3.4e38f;
      for (int e = 0; e < EN; e++) {
        bool used = false;
        for (int q = 0; q < j; q++) if (ch[q] == e) used = true;
        if (!used && w[e] > bv) { bv = w[e]; best = e; }
      }
      ch[j] = best; cv[j] = bv; sum += bv;
    }
    float inv = 1.f / sum;
    for (int j = 0; j < KT; j++) {
      gate_w[tid * KT + j] = cv[j] * inv;
      pair_e[tid * KT + j] = ch[j];
      sel[tid * KT + j] = ch[j];
    }
  }
  for (int i = tid; i < NPAIR * CC; i += 256) mean_raw[i] = 0.f;
  __syncthreads();
  if (tid < EN) {
    int cnt = 0;
    for (int i = 0; i < NPAIR; i++) if (sel[i] == tid) cnt++;
    out_counts[tid] = (float)cnt;
  }
  if (tid < BB * EN) out_weights[tid] = weights[tid];
}

// ---------------- fold LN into conv1/conv4 ----------------
__global__ void fold_kernel(const float* __restrict__ conv1_w, const float* __restrict__ conv1_b,
                            const float* __restrict__ ln1_w, const float* __restrict__ ln1_b,
                            const float* __restrict__ conv4_w, const float* __restrict__ conv4_b,
                            const float* __restrict__ ln2_w, const float* __restrict__ ln2_b,
                            const float* __restrict__ conv3_b, const float* __restrict__ beta,
                            ushort* __restrict__ W1eff, float* __restrict__ b1eff,
                            ushort* __restrict__ W4eff, float* __restrict__ b4eff,
                            float* __restrict__ b3eff) {
  int gid = blockIdx.x * 256 + threadIdx.x;
  if (gid < 2 * EN * DWC) {
    int which = gid / (EN * DWC), rem = gid % (EN * DWC);
    int e = rem / DWC, o = rem % DWC;
    const float* src = (which ? conv4_w : conv1_w) + (size_t)(e * DWC + o) * CC;
    const float* lw = (which ? ln2_w : ln1_w) + e * CC;
    const float* lb = (which ? ln2_b : ln1_b) + e * CC;
    float bacc = (which ? conv4_b : conv1_b)[e * DWC + o];
    ushort* dst = (which ? W4eff : W1eff) + (size_t)(e * DWC + o) * CC;
    for (int c = 0; c < CC; c++) {
      float wv = src[c];
      dst[c] = f2bf(wv * lw[c]);
      bacc += wv * lb[c];
    }
    (which ? b4eff : b1eff)[e * DWC + o] = bacc;
  } else if (gid < 2 * EN * DWC + EN * CC) {
    int x = gid - 2 * EN * DWC;
    b3eff[x] = beta[x] * conv3_b[x];
  }
}

// ---------------- fold2: W5eff[p]=conv5_w[e]*gamma*gate; b5tot ----------------
__global__ void fold2_kernel(const float* __restrict__ conv5_w, const float* __restrict__ conv5_b,
                             const float* __restrict__ gamma, const float* __restrict__ gate_w,
                             const int* __restrict__ pair_e,
                             ushort* __restrict__ W5eff, float* __restrict__ b5tot) {
  int gid = blockIdx.x * 256 + threadIdx.x;
  const int nW = NPAIR * CC * CC / 8;
  if (gid < nW) {
    int base = gid * 8;
    int p = base >> 14, rem = base & 16383;
    int o = rem >> 7, k0 = rem & 127;
    int e = pair_e[p];
    float sc = gamma[e * CC + o] * gate_w[p];
    const float* src = conv5_w + ((size_t)e * CC + o) * CC + k0;
    ushort* dst = W5eff + ((size_t)p * CC + o) * CC + k0;
    for (int q = 0; q < 8; q++) dst[q] = f2bf(src[q] * sc);
  } else if (gid < nW + BB * CC) {
    int x = gid - nW;
    int b = x >> 7, o = x & 127;
    float s = 0.f;
    for (int j = 0; j < KT; j++) {
      int p = b * KT + j, e = pair_e[p];
      s += gate_w[p] * gamma[e * CC + o] * conv5_b[e * CC + o];
    }
    b5tot[x] = s;
  }
}

// ---------------- LN1 + transpose ----------------
__global__ __launch_bounds__(256) void ln1_kernel(const float* __restrict__ feat,
                                                  ushort* __restrict__ xhatT,
                                                  ushort* __restrict__ featT) {
  __shared__ float tile[CC * 64];
  __shared__ float pS[4][64], pS2[4][64], bcM[64], bcR[64];
  int bimg = blockIdx.x >> 6;
  int n0 = (blockIdx.x & 63) * 64;
  int tid = threadIdx.x;
  const float* src = feat + (size_t)bimg * CC * HWP + n0;
#pragma unroll
  for (int i = 0; i < 8; i++) {
    int ch = tid + i * 256;
    int row = ch >> 4, c16 = ch & 15;
    *(float4*)&tile[row * 64 + c16 * 4] = *(const float4*)(src + (size_t)row * HWP + c16 * 4);
  }
  __syncthreads();
  int lane = tid & 63, w = tid >> 6;
  float s = 0.f, s2 = 0.f;
#pragma unroll
  for (int i = 0; i < 32; i++) {
    float v = tile[(w * 32 + i) * 64 + lane];
    s += v; s2 += v * v;
  }
  pS[w][lane] = s; pS2[w][lane] = s2;
  __syncthreads();
  if (w == 0) {
    float t1 = pS[0][lane] + pS[1][lane] + pS[2][lane] + pS[3][lane];
    float t2 = pS2[0][lane] + pS2[1][lane] + pS2[2][lane] + pS2[3][lane];
    float mu = t1 * (1.f / CC);
    float var = t2 * (1.f / CC) - mu * mu;
    bcM[lane] = mu; bcR[lane] = rsqrtf(var + EPSLN);
  }
  __syncthreads();
  float mu = bcM[lane], r = bcR[lane];
  size_t obase = ((size_t)bimg * HWP + n0 + lane) * CC + w * 32;
#pragma unroll
  for (int i = 0; i < 4; i++) {
    float v[8];
#pragma unroll
    for (int q = 0; q < 8; q++) v[q] = tile[(w * 32 + i * 8 + q) * 64 + lane];
    *(ushort4*)(featT + obase + i * 8)     = pack4(v[0], v[1], v[2], v[3]);
    *(ushort4*)(featT + obase + i * 8 + 4) = pack4(v[4], v[5], v[6], v[7]);
    *(ushort4*)(xhatT + obase + i * 8)     = pack4((v[0]-mu)*r, (v[1]-mu)*r, (v[2]-mu)*r, (v[3]-mu)*r);
    *(ushort4*)(xhatT + obase + i * 8 + 4) = pack4((v[4]-mu)*r, (v[5]-mu)*r, (v[6]-mu)*r, (v[7]-mu)*r);
  }
}

// ---------------- shared helpers ----------------
__device__ __forceinline__ void stage_tile(const ushort* __restrict__ g, ushort* lds, int tid) {
#pragma unroll
  for (int i = 0; i < 8; i++) {
    int d = (tid + i * 256) * 16;
    int row = d >> 8;
    uint4 v = *(const uint4*)((const char*)g + d);
    *(uint4*)((char*)lds + (d ^ ((row & 7) << 4))) = v;
  }
}
__device__ __forceinline__ bf16x8 ldfrag(const ushort* lds, int row, int kb) {
  return *(const bf16x8*)((const char*)lds + row * 256 + (kb ^ ((row & 7) << 4)));
}
__device__ __forceinline__ void stage8(ushort* st, int px, int o, ushort4 v) {
  *(ushort4*)((char*)st + px * 256 + ((o * 2) ^ ((px & 7) << 4))) = v;
}

// ---------------- fused conv1 + depthwise3x3 + SimpleGate + mean (v3) ----------------
__global__ __launch_bounds__(256, 3) void c1dw_kernel(
    const ushort* __restrict__ W1eff, const float* __restrict__ b1eff,
    const ushort* __restrict__ xhatT,
    const float* __restrict__ conv2_w, const float* __restrict__ conv2_b,
    const int* __restrict__ pair_e, int pair_lo,
    ushort* __restrict__ yT, float* __restrict__ mean_raw) {
  __shared__ __align__(16) char smem[DWC * TSTRIDE * 2];   // 54272 B
  int ts = blockIdx.x;
  int pc = blockIdx.z, p = pair_lo + pc, e = pair_e[p];
  int img = p / KT;
  int th = (ts >> 3) * 8, tw = (ts & 7) * 8;
  int tid = threadIdx.x, lane = tid & 63, w = tid >> 6;
  int fr = lane & 15, qf = lane >> 4;

#pragma unroll
  for (int i = 0; i < 7; i++) {
    int idx = tid + i * 256;
    if (idx < HPX * 16) {
      int r = idx >> 4, seg = idx & 15;
      int hy = r / HR, hx = r - hy * HR;
      int hh = th + hy - 1, ww = tw + hx - 1;
      int hc = min(max(hh, 0), 63), wc = min(max(ww, 0), 63);
      uint4 v = *(const uint4*)(xhatT + ((size_t)img * HWP + hc * 64 + wc) * CC + seg * 8);
      *(uint4*)(smem + r * 256 + ((seg * 16) ^ ((r & 7) << 4))) = v;
    }
  }
  __syncthreads();

  f32x4 acc[7][4] = {};
#pragma unroll
  for (int ks = 0; ks < 4; ks++) {
    bf16x8 bfr[4];
#pragma unroll
    for (int mf = 0; mf < 4; mf++)
      bfr[mf] = *(const bf16x8*)(W1eff + (size_t)(e * DWC + w * 64 + mf * 16 + fr) * CC + ks * 32 + qf * 8);
#pragma unroll
    for (int nf = 0; nf < 7; nf++) {
      bf16x8 a = ldfrag((const ushort*)smem, nf * 16 + fr, ks * 64 + qf * 16);
#pragma unroll
      for (int mf = 0; mf < 4; mf++)
        acc[nf][mf] = __builtin_amdgcn_mfma_f32_16x16x32_bf16(a, bfr[mf], acc[nf][mf], 0, 0, 0);
    }
  }
  float bias[4];
#pragma unroll
  for (int mf = 0; mf < 4; mf++) bias[mf] = b1eff[e * DWC + w * 64 + mf * 16 + fr];
  __syncthreads();

  ushort* Th = (ushort*)smem;
  int px0q = qf * 4;
#pragma unroll
  for (int nf = 0; nf < 7; nf++) {
    int px = nf * 16 + px0q;
    if (px < HPX) {
#pragma unroll
      for (int mf = 0; mf < 4; mf++) {
        int ch = w * 64 + mf * 16 + fr;
        f32x4 v = acc[nf][mf];
        float bb = bias[mf];
        uint u0 = cvtpk(v.x + bb, v.y + bb);
        uint u1 = cvtpk(v.z + bb, v.w + bb);
        ushort* dst = Th + ch * TSTRIDE + px;
        *(uint*)dst = u0;
        *(uint*)(dst + 2) = u1;
      }
    }
  }
  __syncthreads();

  int cp = tid & 127, ph2 = tid >> 7;
  bool zTop = (ph2 == 0) && (th == 0);
  bool zBot = (ph2 == 1) && (th == 56);
  bool leftE = (tw == 0), rightE = (tw == 56);
  const float* wAp = conv2_w + ((size_t)e * DWC + cp) * 9;
  const float* wGp = conv2_w + ((size_t)(e * DWC + CC) + cp) * 9;
  float wA9[9], wG9[9];
#pragma unroll
  for (int k = 0; k < 9; k++) { wA9[k] = wAp[k]; wG9[k] = wGp[k]; }
  float ba = conv2_b[e * DWC + cp], bg = conv2_b[e * DWC + CC + cp];

  auto loadrowz = [&](float* dst, const ushort* pp, bool zrow) {
    if (zrow) {
#pragma unroll
      for (int q = 0; q < 10; q++) dst[q] = 0.f;
    } else {
#pragma unroll
      for (int q = 0; q < 5; q++) {
        uint u = *(const uint*)(pp + q * 2);
        dst[q * 2]     = bf2f((ushort)(u & 0xffffu));
        dst[q * 2 + 1] = bf2f((ushort)(u >> 16));
      }
      if (leftE) dst[0] = 0.f;
      if (rightE) dst[9] = 0.f;
    }
  };
  auto comp3 = [&](const float* w9, const float* r0, const float* r1, const float* r2, float* out) {
#pragma unroll
    for (int ox = 0; ox < 8; ox++) {
      float a = r0[ox] * w9[0];
      a = fmaf(r0[ox + 1], w9[1], a); a = fmaf(r0[ox + 2], w9[2], a);
      a = fmaf(r1[ox],     w9[3], a); a = fmaf(r1[ox + 1], w9[4], a);
      a = fmaf(r1[ox + 2], w9[5], a);
      a = fmaf(r2[ox],     w9[6], a); a = fmaf(r2[ox + 1], w9[7], a);
      a = fmaf(r2[ox + 2], w9[8], a);
      out[ox] = a;
    }
  };

  float win[3][10];
  float outv[4][8];
  {
    const ushort* rA = Th + cp * TSTRIDE + ph2 * 40;
    loadrowz(win[0], rA, zTop); loadrowz(win[1], rA + 10, false); loadrowz(win[2], rA + 20, false);
    comp3(wA9, win[0], win[1], win[2], outv[0]);
    loadrowz(win[0], rA + 30, false);
    comp3(wA9, win[1], win[2], win[0], outv[1]);
    loadrowz(win[1], rA + 40, false);
    comp3(wA9, win[2], win[0], win[1], outv[2]);
    loadrowz(win[2], rA + 50, zBot);
    comp3(wA9, win[0], win[1], win[2], outv[3]);
  }
  uint ypk[16];
  float csum = 0.f;
  {
    const ushort* rG = Th + (cp + 128) * TSTRIDE + ph2 * 40;
    float gtmp[8];
    loadrowz(win[0], rG, zTop); loadrowz(win[1], rG + 10, false); loadrowz(win[2], rG + 20, false);
#pragma unroll
    for (int oy = 0; oy < 4; oy++) {
      if (oy == 1) { loadrowz(win[0], rG + 30, false); }
      if (oy == 2) { loadrowz(win[1], rG + 40, false); }
      if (oy == 3) { loadrowz(win[2], rG + 50, zBot); }
      const float* r0 = (oy == 0) ? win[0] : (oy == 1) ? win[1] : (oy == 2) ? win[2] : win[0];
      const float* r1 = (oy == 0) ? win[1] : (oy == 1) ? win[2] : (oy == 2) ? win[0] : win[1];
      const float* r2 = (oy == 0) ? win[2] : (oy == 1) ? win[0] : (oy == 2) ? win[1] : win[2];
      comp3(wG9, r0, r1, r2, gtmp);
#pragma unroll
      for (int ox = 0; ox < 8; ox += 2) {
        float y0 = (outv[oy][ox]     + ba) * (gtmp[ox]     + bg);
        float y1 = (outv[oy][ox + 1] + ba) * (gtmp[ox + 1] + bg);
        csum += y0 + y1;
        ypk[oy * 4 + (ox >> 1)] = cvtpk(y0, y1);
      }
    }
  }
  __syncthreads();

  float* psum = (float*)(smem + 16384);
#pragma unroll
  for (int oy = 0; oy < 4; oy++)
#pragma unroll
    for (int ox = 0; ox < 8; ox++) {
      int opx = (ph2 * 4 + oy) * 8 + ox;
      uint pkv = ypk[oy * 4 + (ox >> 1)];
      ushort val = (ox & 1) ? (ushort)(pkv >> 16) : (ushort)(pkv & 0xffffu);
      *(ushort*)(smem + opx * 256 + ((cp * 2) ^ ((opx & 7) << 4))) = val;
    }
  psum[tid] = csum;
  __syncthreads();
#pragma unroll
  for (int i = 0; i < 4; i++) {
    int idx = tid + i * 256;
    int opx = idx >> 4, ck = idx & 15;
    uint4 v = *(const uint4*)(smem + opx * 256 + ((ck * 16) ^ ((opx & 7) << 4)));
    int n = (th + (opx >> 3)) * 64 + tw + (opx & 7);
    *(uint4*)((char*)(yT + ((size_t)pc * HWP + n) * CC) + ck * 16) = v;
  }
  if (tid < CC) {
    atomicAdd(&mean_raw[p * CC + tid], psum[tid] + psum[CC + tid]);
  }
}

// ---------------- SCA + W3eff fold merged ----------------
__global__ void sca_w3fold_kernel(const float* __restrict__ mean_raw,
                                  const float* __restrict__ sca_w, const float* __restrict__ sca_b,
                                  const float* __restrict__ conv3_w, const float* __restrict__ beta,
                                  const int* __restrict__ pair_e, int pair_lo,
                                  ushort* __restrict__ W3eff) {
  __shared__ float m[CC];
  __shared__ float sv[CC];
  int pc = blockIdx.x, p = pair_lo + pc, e = pair_e[p];
  int tid = threadIdx.x;
  if (tid < CC) m[tid] = mean_raw[p * CC + tid] * (1.f / HWP);
  __syncthreads();
  if (tid < CC) {
    const float* wr = sca_w + (size_t)(e * CC + tid) * CC;
    float acc = sca_b[e * CC + tid];
#pragma unroll 8
    for (int c = 0; c < CC; c++) acc = fmaf(wr[c], m[c], acc);
    sv[tid] = acc;
  }
  __syncthreads();
#pragma unroll
  for (int i = 0; i < 8; i++) {
    int idx = tid + i * 256;
    int o = idx >> 4, k0 = (idx & 15) * 8;
    float bt = beta[e * CC + o];
    const float* src = conv3_w + ((size_t)e * CC + o) * CC + k0;
    ushort* dst = W3eff + ((size_t)pc * CC + o) * CC + k0;
#pragma unroll
    for (int q = 0; q < 8; q++) dst[q] = f2bf(src[q] * sv[k0 + q] * bt);
  }
}

// ---------------- naf2 v2: conv3+LN2+conv4+SG+conv5; W from global (L2), XCD-clustered ----------------
__global__ __launch_bounds__(256, 3) void naf2_kernel(
    const ushort* __restrict__ W3eff, const float* __restrict__ b3eff,
    const ushort* __restrict__ W4eff, const float* __restrict__ b4eff,
    const ushort* __restrict__ W5eff, const float* __restrict__ b5tot,
    const ushort* __restrict__ yT, const ushort* __restrict__ featT,
    const float* __restrict__ gate_w, const int* __restrict__ pair_e, int pair_lo,
    int nsamp, float* __restrict__ out) {
  __shared__ ushort As[CC * CC];     // 32KB activation tile
  __shared__ float2 red2[256];       // LN2 stats
  int wg = blockIdx.x;
  int sl, tx;
  if (nsamp == 16) {                 // XCD k owns samples 2k, 2k+1 -> weights L2-resident
    int xcd = wg & 7, li = wg >> 3;
    sl = xcd * 2 + (li >> 5);
    tx = li & 31;
  } else {
    sl = wg >> 5;
    tx = wg & 31;
  }
  int n0 = tx * 128;
  int b = pair_lo / KT + sl;
  int tid = threadIdx.x, lane = tid & 63, w = tid >> 6;
  int wr = w >> 1, wc = w & 1, fr = lane & 15, qf = lane >> 4;
  int kb0 = qf * 16, og = qf * 4;
  f32x4 acc5[4][4] = {};
  f32x4 xres[4][4] = {};

  // direct-global A-operand GEMM: W rows from L2, act from As
  auto gemmW = [&](const ushort* __restrict__ W, f32x4 (&acc)[4][4]) {
#pragma unroll
    for (int ks = 0; ks < 4; ks++) {
      bf16x8 a[4], bb[4];
#pragma unroll
      for (int m = 0; m < 4; m++)
        a[m] = *(const bf16x8*)(W + (size_t)(wr * 64 + m * 16 + fr) * CC + ks * 32 + qf * 8);
#pragma unroll
      for (int n = 0; n < 4; n++) bb[n] = ldfrag(As, wc * 64 + n * 16 + fr, ks * 64 + kb0);
#pragma unroll
      for (int m = 0; m < 4; m++)
#pragma unroll
        for (int n = 0; n < 4; n++)
          acc[m][n] = __builtin_amdgcn_mfma_f32_16x16x32_bf16(a[m], bb[n], acc[m][n], 0, 0, 0);
    }
  };

  for (int j = 0; j < KT; j++) {
    int pc = sl * KT + j, p = pair_lo + pc, e = pair_e[p];
    float gw = gate_w[p];
    __syncthreads();                  // prior iter's conv5 As reads done
    stage_tile(yT + ((size_t)pc * HWP + n0) * CC, As, tid);
    __syncthreads();
    // --- conv3 ---
    f32x4 acc3[4][4] = {};
    gemmW(W3eff + (size_t)pc * CC * CC, acc3);
    // --- x1 = feat + acc3 + b3eff; xres += gw*x1; LN2 stats ---
    float s[4] = {}, s2[4] = {};
#pragma unroll
    for (int m = 0; m < 4; m++) {
      int o = wr * 64 + m * 16 + og;
      float4 bvv = *(const float4*)&b3eff[e * CC + o];
#pragma unroll
      for (int n = 0; n < 4; n++) {
        int px = wc * 64 + n * 16 + fr;
        ushort4 f4 = *(const ushort4*)(featT + ((size_t)b * HWP + n0 + px) * CC + o);
        f32x4 v = acc3[m][n];
        v.x += bf2f(f4.x) + bvv.x; v.y += bf2f(f4.y) + bvv.y;
        v.z += bf2f(f4.z) + bvv.z; v.w += bf2f(f4.w) + bvv.w;
        acc3[m][n] = v;
        f32x4 xr = xres[m][n];
        xr.x += gw * v.x; xr.y += gw * v.y; xr.z += gw * v.z; xr.w += gw * v.w;
        xres[m][n] = xr;
        s[n] += v.x + v.y + v.z + v.w;
        s2[n] += v.x * v.x + v.y * v.y + v.z * v.z + v.w * v.w;
      }
    }
#pragma unroll
    for (int n = 0; n < 4; n++) {
      s[n] += __shfl_xor(s[n], 16, 64); s[n] += __shfl_xor(s[n], 32, 64);
      s2[n] += __shfl_xor(s2[n], 16, 64); s2[n] += __shfl_xor(s2[n], 32, 64);
    }
    if (lane < 16) {
#pragma unroll
      for (int n = 0; n < 4; n++) {
        float2 v; v.x = s[n]; v.y = s2[n];
        red2[wr * 128 + wc * 64 + n * 16 + fr] = v;
      }
    }
    __syncthreads();                  // red2 written AND conv3 As reads done
    float mu[4], rs[4];
#pragma unroll
    for (int n = 0; n < 4; n++) {
      int px = wc * 64 + n * 16 + fr;
      float2 r0 = red2[px], r1 = red2[128 + px];
      float m_ = (r0.x + r1.x) * (1.f / CC);
      float var = (r0.y + r1.y) * (1.f / CC) - m_ * m_;
      mu[n] = m_; rs[n] = rsqrtf(var + EPSLN);
    }
    // xh2 -> As (disjoint per-wave rectangles; red2 is separate memory)
#pragma unroll
    for (int m = 0; m < 4; m++) {
      int o = wr * 64 + m * 16 + og;
#pragma unroll
      for (int n = 0; n < 4; n++) {
        int px = wc * 64 + n * 16 + fr;
        f32x4 v = acc3[m][n];
        stage8(As, px, o, pack4((v.x - mu[n]) * rs[n], (v.y - mu[n]) * rs[n],
                                (v.z - mu[n]) * rs[n], (v.w - mu[n]) * rs[n]));
      }
    }
    __syncthreads();                  // xh2 complete
    // --- conv4 half A then half G (both read-only on As; no barrier between) ---
    f32x4 accA[4][4] = {};
    gemmW(W4eff + (size_t)e * DWC * CC, accA);
    uint pA[4][4][2];
#pragma unroll
    for (int m = 0; m < 4; m++) {
      int o = wr * 64 + m * 16 + og;
      float4 ba4 = *(const float4*)&b4eff[e * DWC + o];
#pragma unroll
      for (int n = 0; n < 4; n++) {
        f32x4 v = accA[m][n];
        pA[m][n][0] = cvtpk(v.x + ba4.x, v.y + ba4.y);
        pA[m][n][1] = cvtpk(v.z + ba4.z, v.w + ba4.w);
      }
    }
    f32x4 accG[4][4] = {};
    gemmW(W4eff + ((size_t)e * DWC + CC) * CC, accG);
    __syncthreads();                  // xh2 reads done
    // --- SG -> g5 into As ---
#pragma unroll
    for (int m = 0; m < 4; m++) {
      int o = wr * 64 + m * 16 + og;
      float4 bg4 = *(const float4*)&b4eff[e * DWC + CC + o];
#pragma unroll
      for (int n = 0; n < 4; n++) {
        int px = wc * 64 + n * 16 + fr;
        f32x4 vg = accG[m][n];
        uint u0 = pA[m][n][0], u1 = pA[m][n][1];
        float g0 = bf2f((ushort)(u0 & 0xffffu)) * (vg.x + bg4.x);
        float g1 = bf2f((ushort)(u0 >> 16))     * (vg.y + bg4.y);
        float g2 = bf2f((ushort)(u1 & 0xffffu)) * (vg.z + bg4.z);
        float g3 = bf2f((ushort)(u1 >> 16))     * (vg.w + bg4.w);
        stage8(As, px, o, pack4(g0, g1, g2, g3));
      }
    }
    __syncthreads();                  // g5 complete
    // --- conv5 accumulate ---
    gemmW(W5eff + (size_t)p * CC * CC, acc5);
  }
  // --- epilogue: out = acc5 + b5tot + xres ---
  __syncthreads();
  ushort* Ct = As;
#pragma unroll
  for (int m = 0; m < 4; m++) {
    int o = wr * 64 + m * 16 + og;
    float4 bt = *(const float4*)&b5tot[b * CC + o];
#pragma unroll
    for (int n = 0; n < 4; n++) {
      int px = wc * 64 + n * 16 + fr;
      f32x4 v = acc5[m][n];
      f32x4 xr = xres[m][n];
      float r0 = v.x + bt.x + xr.x;
      float r1 = v.y + bt.y + xr.y;
      float r2 = v.z + bt.z + xr.z;
      float r3 = v.w + bt.w + xr.w;
      *(ushort*)((char*)Ct + (o+0) * 256 + ((px*2) ^ (((o+0) & 7) << 4))) = f2bf1(r0);
      *(ushort*)((char*)Ct + (o+1) * 256 + ((px*2) ^ (((o+1) & 7) << 4))) = f2bf1(r1);
      *(ushort*)((char*)Ct + (o+2) * 256 + ((px*2) ^ (((o+2) & 7) << 4))) = f2bf1(r2);
      *(ushort*)((char*)Ct + (o+3) * 256 + ((px*2) ^ (((o+3) & 7) << 4))) = f2bf1(r3);
    }
  }
  __syncthreads();
  int o = tid >> 1, ph = (tid & 1) * 64;
  float* orow = out + ((size_t)(b * CC + o)) * HWP + n0 + ph;
  int swz = (o & 7) << 4;
#pragma unroll
  for (int i = 0; i < 8; i++) {
    const ushort* lp = (const ushort*)((const char*)Ct + o * 256 + ((ph * 2 + i * 16) ^ swz));
    float4 f0, f1;
    f0.x = bf2f(lp[0]); f0.y = bf2f(lp[1]); f0.z = bf2f(lp[2]); f0.w = bf2f(lp[3]);
    f1.x = bf2f(lp[4]); f1.y = bf2f(lp[5]); f1.z = bf2f(lp[6]); f1.w = bf2f(lp[7]);
    *(float4*)(orow + i * 8) = f0;
    *(float4*)(orow + i * 8 + 4) = f1;
  }
}

extern "C" void kernel_launch(void* const* d_in, const int* in_sizes, int n_in,
                              void* d_out, int out_size, void* d_ws, size_t ws_size,
                              hipStream_t stream) {
  const float* feat    = (const float*)d_in[0];
  const float* weights = (const float*)d_in[1];
  const float* ln1_w   = (const float*)d_in[2];
  const float* ln1_b   = (const float*)d_in[3];
  const float* conv1_w = (const float*)d_in[4];
  const float* conv1_b = (const float*)d_in[5];
  const float* conv2_w = (const float*)d_in[6];
  const float* conv2_b = (const float*)d_in[7];
  const float* sca_w   = (const float*)d_in[8];
  const float* sca_b   = (const float*)d_in[9];
  const float* conv3_w = (const float*)d_in[10];
  const float* conv3_b = (const float*)d_in[11];
  const float* ln2_w   = (const float*)d_in[12];
  const float* ln2_b   = (const float*)d_in[13];
  const float* conv4_w = (const float*)d_in[14];
  const float* conv4_b = (const float*)d_in[15];
  const float* conv5_w = (const float*)d_in[16];
  const float* conv5_b = (const float*)d_in[17];
  const float* beta    = (const float*)d_in[18];
  const float* gamma   = (const float*)d_in[19];

  float* out = (float*)d_out;
  float* out_counts = out + (size_t)BB * CC * HWP;
  float* out_weights = out_counts + EN;

  char* base = (char*)d_ws;
  size_t off = 0;
  auto carveU = [&](size_t n) -> ushort* { ushort* p = (ushort*)(base + off); off += n * 2; return p; };
  auto carveF = [&](size_t n) -> float* { float* p = (float*)(base + off); off += n * 4; return p; };

  ushort* W1eff = carveU((size_t)EN * DWC * CC);
  ushort* W4eff = carveU((size_t)EN * DWC * CC);
  ushort* W5eff = carveU((size_t)NPAIR * CC * CC);
  ushort* W3eff = carveU((size_t)NPAIR * CC * CC);
  float* b1eff  = carveF(EN * DWC);
  float* b4eff  = carveF(EN * DWC);
  float* b3eff  = carveF(EN * CC);
  float* b5tot  = carveF(BB * CC);
  float* gate_w = carveF(64);
  int*   pair_e = (int*)carveF(64);
  float* mean_raw = carveF(NPAIR * CC);
  ushort* xhatT = carveU((size_t)BB * HWP * CC);
  ushort* featT = carveU((size_t)BB * HWP * CC);

  // per-pair: y only (1MB)
  const size_t per_pair = (size_t)HWP * CC * 2;
  int ns = 16;
  while (ns > 1 && off + (size_t)ns * KT * per_pair > ws_size) ns >>= 1;
  size_t pr = (size_t)ns * KT;
  ushort* y_T = carveU(pr * HWP * CC);

  gate_kernel<<<1, 256, 0, stream>>>(weights, gate_w, pair_e, out_counts, out_weights, mean_raw);
  fold_kernel<<<13, 256, 0, stream>>>(conv1_w, conv1_b, ln1_w, ln1_b,
                                      conv4_w, conv4_b, ln2_w, ln2_b,
                                      conv3_b, beta, W1eff, b1eff, W4eff, b4eff, b3eff);
  fold2_kernel<<<393, 256, 0, stream>>>(conv5_w, conv5_b, gamma, gate_w, pair_e, W5eff, b5tot);
  ln1_kernel<<<BB * 64, 256, 0, stream>>>(feat, xhatT, featT);

  for (int s0 = 0; s0 < BB; s0 += ns) {
    int np = ns * KT, plo = s0 * KT;
    c1dw_kernel<<<dim3(64, 1, np), 256, 0, stream>>>(W1eff, b1eff, xhatT, conv2_w, conv2_b,
                                                     pair_e, plo, y_T, mean_raw);
    sca_w3fold_kernel<<<np, 256, 0, stream>>>(mean_raw, sca_w, sca_b, conv3_w, beta,
                                              pair_e, plo, W3eff);
    naf2_kernel<<<dim3(32 * ns, 1, 1), 256, 0, stream>>>(W3eff, b3eff, W4eff, b4eff, W5eff, b5tot,
                                                         y_T, featT, gate_w, pair_e, plo, ns, out);
  }
}

// Round 11
// 200.149 us; speedup vs baseline: 1.7522x; 1.7522x over previous
//
#include <hip/hip_runtime.h>

#define EN 5
#define KT 3
#define BB 16
#define CC 128
#define HWP 4096
#define DWC 256
#define NPAIR 48
#define EPSLN 1e-6f
#define HR 10
#define HPX 100
#define TSTRIDE 106

typedef float f32x4 __attribute__((ext_vector_type(4)));
typedef __bf16 bf16x8 __attribute__((ext_vector_type(8)));

__device__ __forceinline__ float bf2f(ushort u) {
  union { unsigned int u; float f; } v; v.u = ((unsigned int)u) << 16; return v.f;
}
__device__ __forceinline__ uint cvtpk(float lo, float hi) {
  uint r;
  asm("v_cvt_pk_bf16_f32 %0, %1, %2" : "=v"(r) : "v"(lo), "v"(hi));
  return r;
}
__device__ __forceinline__ ushort f2bf(float f) {
  union { float f; unsigned int u; } v; v.f = f;
  unsigned int r = v.u + 0x7FFFu + ((v.u >> 16) & 1u);
  return (ushort)(r >> 16);
}
__device__ __forceinline__ ushort f2bf1(float f) {
  return (ushort)(cvtpk(f, f) & 0xffffu);
}
__device__ __forceinline__ ushort4 pack4(float a, float b, float c, float d) {
  union { uint2 u; ushort4 s; } v;
  v.u.x = cvtpk(a, b);
  v.u.y = cvtpk(c, d);
  return v.s;
}

// ---------------- gate ----------------
__global__ void gate_kernel(const float* __restrict__ weights, float* __restrict__ gate_w,
                            int* __restrict__ pair_e, float* __restrict__ out_counts,
                            float* __restrict__ out_weights, float* __restrict__ mean_raw) {
  __shared__ int sel[NPAIR];
  int tid = threadIdx.x;
  if (tid < BB) {
    float w[EN];
    for (int e = 0; e < EN; e++) w[e] = weights[tid * EN + e];
    int ch[KT]; float cv[KT]; float sum = 0.f;
    for (int j = 0; j < KT; j++) {
      int best = -1; float bv = -3.4e38f;
      for (int e = 0; e < EN; e++) {
        bool used = false;
        for (int q = 0; q < j; q++) if (ch[q] == e) used = true;
        if (!used && w[e] > bv) { bv = w[e]; best = e; }
      }
      ch[j] = best; cv[j] = bv; sum += bv;
    }
    float inv = 1.f / sum;
    for (int j = 0; j < KT; j++) {
      gate_w[tid * KT + j] = cv[j] * inv;
      pair_e[tid * KT + j] = ch[j];
      sel[tid * KT + j] = ch[j];
    }
  }
  for (int i = tid; i < NPAIR * CC; i += 256) mean_raw[i] = 0.f;
  __syncthreads();
  if (tid < EN) {
    int cnt = 0;
    for (int i = 0; i < NPAIR; i++) if (sel[i] == tid) cnt++;
    out_counts[tid] = (float)cnt;
  }
  if (tid < BB * EN) out_weights[tid] = weights[tid];
}

// ---------------- fold LN into conv1/conv4 ----------------
__global__ void fold_kernel(const float* __restrict__ conv1_w, const float* __restrict__ conv1_b,
                            const float* __restrict__ ln1_w, const float* __restrict__ ln1_b,
                            const float* __restrict__ conv4_w, const float* __restrict__ conv4_b,
                            const float* __restrict__ ln2_w, const float* __restrict__ ln2_b,
                            const float* __restrict__ conv3_b, const float* __restrict__ beta,
                            ushort* __restrict__ W1eff, float* __restrict__ b1eff,
                            ushort* __restrict__ W4eff, float* __restrict__ b4eff,
                            float* __restrict__ b3eff) {
  int gid = blockIdx.x * 256 + threadIdx.x;
  if (gid < 2 * EN * DWC) {
    int which = gid / (EN * DWC), rem = gid % (EN * DWC);
    int e = rem / DWC, o = rem % DWC;
    const float* src = (which ? conv4_w : conv1_w) + (size_t)(e * DWC + o) * CC;
    const float* lw = (which ? ln2_w : ln1_w) + e * CC;
    const float* lb = (which ? ln2_b : ln1_b) + e * CC;
    float bacc = (which ? conv4_b : conv1_b)[e * DWC + o];
    ushort* dst = (which ? W4eff : W1eff) + (size_t)(e * DWC + o) * CC;
    for (int c = 0; c < CC; c++) {
      float wv = src[c];
      dst[c] = f2bf(wv * lw[c]);
      bacc += wv * lb[c];
    }
    (which ? b4eff : b1eff)[e * DWC + o] = bacc;
  } else if (gid < 2 * EN * DWC + EN * CC) {
    int x = gid - 2 * EN * DWC;
    b3eff[x] = beta[x] * conv3_b[x];
  }
}

// ---------------- fold2: W5eff[p]=conv5_w[e]*gamma*gate; b5tot ----------------
__global__ void fold2_kernel(const float* __restrict__ conv5_w, const float* __restrict__ conv5_b,
                             const float* __restrict__ gamma, const float* __restrict__ gate_w,
                             const int* __restrict__ pair_e,
                             ushort* __restrict__ W5eff, float* __restrict__ b5tot) {
  int gid = blockIdx.x * 256 + threadIdx.x;
  const int nW = NPAIR * CC * CC / 8;
  if (gid < nW) {
    int base = gid * 8;
    int p = base >> 14, rem = base & 16383;
    int o = rem >> 7, k0 = rem & 127;
    int e = pair_e[p];
    float sc = gamma[e * CC + o] * gate_w[p];
    const float* src = conv5_w + ((size_t)e * CC + o) * CC + k0;
    ushort* dst = W5eff + ((size_t)p * CC + o) * CC + k0;
    for (int q = 0; q < 8; q++) dst[q] = f2bf(src[q] * sc);
  } else if (gid < nW + BB * CC) {
    int x = gid - nW;
    int b = x >> 7, o = x & 127;
    float s = 0.f;
    for (int j = 0; j < KT; j++) {
      int p = b * KT + j, e = pair_e[p];
      s += gate_w[p] * gamma[e * CC + o] * conv5_b[e * CC + o];
    }
    b5tot[x] = s;
  }
}

// ---------------- LN1 + transpose ----------------
__global__ __launch_bounds__(256) void ln1_kernel(const float* __restrict__ feat,
                                                  ushort* __restrict__ xhatT,
                                                  ushort* __restrict__ featT) {
  __shared__ float tile[CC * 64];
  __shared__ float pS[4][64], pS2[4][64], bcM[64], bcR[64];
  int bimg = blockIdx.x >> 6;
  int n0 = (blockIdx.x & 63) * 64;
  int tid = threadIdx.x;
  const float* src = feat + (size_t)bimg * CC * HWP + n0;
#pragma unroll
  for (int i = 0; i < 8; i++) {
    int ch = tid + i * 256;
    int row = ch >> 4, c16 = ch & 15;
    *(float4*)&tile[row * 64 + c16 * 4] = *(const float4*)(src + (size_t)row * HWP + c16 * 4);
  }
  __syncthreads();
  int lane = tid & 63, w = tid >> 6;
  float s = 0.f, s2 = 0.f;
#pragma unroll
  for (int i = 0; i < 32; i++) {
    float v = tile[(w * 32 + i) * 64 + lane];
    s += v; s2 += v * v;
  }
  pS[w][lane] = s; pS2[w][lane] = s2;
  __syncthreads();
  if (w == 0) {
    float t1 = pS[0][lane] + pS[1][lane] + pS[2][lane] + pS[3][lane];
    float t2 = pS2[0][lane] + pS2[1][lane] + pS2[2][lane] + pS2[3][lane];
    float mu = t1 * (1.f / CC);
    float var = t2 * (1.f / CC) - mu * mu;
    bcM[lane] = mu; bcR[lane] = rsqrtf(var + EPSLN);
  }
  __syncthreads();
  float mu = bcM[lane], r = bcR[lane];
  size_t obase = ((size_t)bimg * HWP + n0 + lane) * CC + w * 32;
#pragma unroll
  for (int i = 0; i < 4; i++) {
    float v[8];
#pragma unroll
    for (int q = 0; q < 8; q++) v[q] = tile[(w * 32 + i * 8 + q) * 64 + lane];
    *(ushort4*)(featT + obase + i * 8)     = pack4(v[0], v[1], v[2], v[3]);
    *(ushort4*)(featT + obase + i * 8 + 4) = pack4(v[4], v[5], v[6], v[7]);
    *(ushort4*)(xhatT + obase + i * 8)     = pack4((v[0]-mu)*r, (v[1]-mu)*r, (v[2]-mu)*r, (v[3]-mu)*r);
    *(ushort4*)(xhatT + obase + i * 8 + 4) = pack4((v[4]-mu)*r, (v[5]-mu)*r, (v[6]-mu)*r, (v[7]-mu)*r);
  }
}

// ---------------- shared helpers ----------------
__device__ __forceinline__ void stage_tile(const ushort* __restrict__ g, ushort* lds, int tid) {
#pragma unroll
  for (int i = 0; i < 8; i++) {
    int d = (tid + i * 256) * 16;
    int row = d >> 8;
    uint4 v = *(const uint4*)((const char*)g + d);
    *(uint4*)((char*)lds + (d ^ ((row & 7) << 4))) = v;
  }
}
__device__ __forceinline__ bf16x8 ldfrag(const ushort* lds, int row, int kb) {
  return *(const bf16x8*)((const char*)lds + row * 256 + (kb ^ ((row & 7) << 4)));
}
__device__ __forceinline__ void stage8(ushort* st, int px, int o, ushort4 v) {
  *(ushort4*)((char*)st + px * 256 + ((o * 2) ^ ((px & 7) << 4))) = v;
}
__device__ __forceinline__ uint4 ldstage16(const ushort* st, int px, int ck) {
  return *(const uint4*)((const char*)st + px * 256 + ((ck * 16) ^ ((px & 7) << 4)));
}

// ---------------- fused conv1 + depthwise3x3 + SimpleGate + mean (v3) ----------------
__global__ __launch_bounds__(256, 3) void c1dw_kernel(
    const ushort* __restrict__ W1eff, const float* __restrict__ b1eff,
    const ushort* __restrict__ xhatT,
    const float* __restrict__ conv2_w, const float* __restrict__ conv2_b,
    const int* __restrict__ pair_e, int pair_lo,
    ushort* __restrict__ yT, float* __restrict__ mean_raw) {
  __shared__ __align__(16) char smem[DWC * TSTRIDE * 2];   // 54272 B
  int ts = blockIdx.x;
  int pc = blockIdx.z, p = pair_lo + pc, e = pair_e[p];
  int img = p / KT;
  int th = (ts >> 3) * 8, tw = (ts & 7) * 8;
  int tid = threadIdx.x, lane = tid & 63, w = tid >> 6;
  int fr = lane & 15, qf = lane >> 4;

#pragma unroll
  for (int i = 0; i < 7; i++) {
    int idx = tid + i * 256;
    if (idx < HPX * 16) {
      int r = idx >> 4, seg = idx & 15;
      int hy = r / HR, hx = r - hy * HR;
      int hh = th + hy - 1, ww = tw + hx - 1;
      int hc = min(max(hh, 0), 63), wc = min(max(ww, 0), 63);
      uint4 v = *(const uint4*)(xhatT + ((size_t)img * HWP + hc * 64 + wc) * CC + seg * 8);
      *(uint4*)(smem + r * 256 + ((seg * 16) ^ ((r & 7) << 4))) = v;
    }
  }
  __syncthreads();

  f32x4 acc[7][4] = {};
#pragma unroll
  for (int ks = 0; ks < 4; ks++) {
    bf16x8 bfr[4];
#pragma unroll
    for (int mf = 0; mf < 4; mf++)
      bfr[mf] = *(const bf16x8*)(W1eff + (size_t)(e * DWC + w * 64 + mf * 16 + fr) * CC + ks * 32 + qf * 8);
#pragma unroll
    for (int nf = 0; nf < 7; nf++) {
      bf16x8 a = ldfrag((const ushort*)smem, nf * 16 + fr, ks * 64 + qf * 16);
#pragma unroll
      for (int mf = 0; mf < 4; mf++)
        acc[nf][mf] = __builtin_amdgcn_mfma_f32_16x16x32_bf16(a, bfr[mf], acc[nf][mf], 0, 0, 0);
    }
  }
  float bias[4];
#pragma unroll
  for (int mf = 0; mf < 4; mf++) bias[mf] = b1eff[e * DWC + w * 64 + mf * 16 + fr];
  __syncthreads();

  ushort* Th = (ushort*)smem;
  int px0q = qf * 4;
#pragma unroll
  for (int nf = 0; nf < 7; nf++) {
    int px = nf * 16 + px0q;
    if (px < HPX) {
#pragma unroll
      for (int mf = 0; mf < 4; mf++) {
        int ch = w * 64 + mf * 16 + fr;
        f32x4 v = acc[nf][mf];
        float bb = bias[mf];
        uint u0 = cvtpk(v.x + bb, v.y + bb);
        uint u1 = cvtpk(v.z + bb, v.w + bb);
        ushort* dst = Th + ch * TSTRIDE + px;
        *(uint*)dst = u0;
        *(uint*)(dst + 2) = u1;
      }
    }
  }
  __syncthreads();

  int cp = tid & 127, ph2 = tid >> 7;
  bool zTop = (ph2 == 0) && (th == 0);
  bool zBot = (ph2 == 1) && (th == 56);
  bool leftE = (tw == 0), rightE = (tw == 56);
  const float* wAp = conv2_w + ((size_t)e * DWC + cp) * 9;
  const float* wGp = conv2_w + ((size_t)(e * DWC + CC) + cp) * 9;
  float wA9[9], wG9[9];
#pragma unroll
  for (int k = 0; k < 9; k++) { wA9[k] = wAp[k]; wG9[k] = wGp[k]; }
  float ba = conv2_b[e * DWC + cp], bg = conv2_b[e * DWC + CC + cp];

  auto loadrowz = [&](float* dst, const ushort* pp, bool zrow) {
    if (zrow) {
#pragma unroll
      for (int q = 0; q < 10; q++) dst[q] = 0.f;
    } else {
#pragma unroll
      for (int q = 0; q < 5; q++) {
        uint u = *(const uint*)(pp + q * 2);
        dst[q * 2]     = bf2f((ushort)(u & 0xffffu));
        dst[q * 2 + 1] = bf2f((ushort)(u >> 16));
      }
      if (leftE) dst[0] = 0.f;
      if (rightE) dst[9] = 0.f;
    }
  };
  auto comp3 = [&](const float* w9, const float* r0, const float* r1, const float* r2, float* out) {
#pragma unroll
    for (int ox = 0; ox < 8; ox++) {
      float a = r0[ox] * w9[0];
      a = fmaf(r0[ox + 1], w9[1], a); a = fmaf(r0[ox + 2], w9[2], a);
      a = fmaf(r1[ox],     w9[3], a); a = fmaf(r1[ox + 1], w9[4], a);
      a = fmaf(r1[ox + 2], w9[5], a);
      a = fmaf(r2[ox],     w9[6], a); a = fmaf(r2[ox + 1], w9[7], a);
      a = fmaf(r2[ox + 2], w9[8], a);
      out[ox] = a;
    }
  };

  float win[3][10];
  float outv[4][8];
  {
    const ushort* rA = Th + cp * TSTRIDE + ph2 * 40;
    loadrowz(win[0], rA, zTop); loadrowz(win[1], rA + 10, false); loadrowz(win[2], rA + 20, false);
    comp3(wA9, win[0], win[1], win[2], outv[0]);
    loadrowz(win[0], rA + 30, false);
    comp3(wA9, win[1], win[2], win[0], outv[1]);
    loadrowz(win[1], rA + 40, false);
    comp3(wA9, win[2], win[0], win[1], outv[2]);
    loadrowz(win[2], rA + 50, zBot);
    comp3(wA9, win[0], win[1], win[2], outv[3]);
  }
  uint ypk[16];
  float csum = 0.f;
  {
    const ushort* rG = Th + (cp + 128) * TSTRIDE + ph2 * 40;
    float gtmp[8];
    loadrowz(win[0], rG, zTop); loadrowz(win[1], rG + 10, false); loadrowz(win[2], rG + 20, false);
#pragma unroll
    for (int oy = 0; oy < 4; oy++) {
      if (oy == 1) { loadrowz(win[0], rG + 30, false); }
      if (oy == 2) { loadrowz(win[1], rG + 40, false); }
      if (oy == 3) { loadrowz(win[2], rG + 50, zBot); }
      const float* r0 = (oy == 0) ? win[0] : (oy == 1) ? win[1] : (oy == 2) ? win[2] : win[0];
      const float* r1 = (oy == 0) ? win[1] : (oy == 1) ? win[2] : (oy == 2) ? win[0] : win[1];
      const float* r2 = (oy == 0) ? win[2] : (oy == 1) ? win[0] : (oy == 2) ? win[1] : win[2];
      comp3(wG9, r0, r1, r2, gtmp);
#pragma unroll
      for (int ox = 0; ox < 8; ox += 2) {
        float y0 = (outv[oy][ox]     + ba) * (gtmp[ox]     + bg);
        float y1 = (outv[oy][ox + 1] + ba) * (gtmp[ox + 1] + bg);
        csum += y0 + y1;
        ypk[oy * 4 + (ox >> 1)] = cvtpk(y0, y1);
      }
    }
  }
  __syncthreads();

  float* psum = (float*)(smem + 16384);
#pragma unroll
  for (int oy = 0; oy < 4; oy++)
#pragma unroll
    for (int ox = 0; ox < 8; ox++) {
      int opx = (ph2 * 4 + oy) * 8 + ox;
      uint pkv = ypk[oy * 4 + (ox >> 1)];
      ushort val = (ox & 1) ? (ushort)(pkv >> 16) : (ushort)(pkv & 0xffffu);
      *(ushort*)(smem + opx * 256 + ((cp * 2) ^ ((opx & 7) << 4))) = val;
    }
  psum[tid] = csum;
  __syncthreads();
#pragma unroll
  for (int i = 0; i < 4; i++) {
    int idx = tid + i * 256;
    int opx = idx >> 4, ck = idx & 15;
    uint4 v = *(const uint4*)(smem + opx * 256 + ((ck * 16) ^ ((opx & 7) << 4)));
    int n = (th + (opx >> 3)) * 64 + tw + (opx & 7);
    *(uint4*)((char*)(yT + ((size_t)pc * HWP + n) * CC) + ck * 16) = v;
  }
  if (tid < CC) {
    atomicAdd(&mean_raw[p * CC + tid], psum[tid] + psum[CC + tid]);
  }
}

// ---------------- SCA + W3eff fold merged ----------------
__global__ void sca_w3fold_kernel(const float* __restrict__ mean_raw,
                                  const float* __restrict__ sca_w, const float* __restrict__ sca_b,
                                  const float* __restrict__ conv3_w, const float* __restrict__ beta,
                                  const int* __restrict__ pair_e, int pair_lo,
                                  ushort* __restrict__ W3eff) {
  __shared__ float m[CC];
  __shared__ float sv[CC];
  int pc = blockIdx.x, p = pair_lo + pc, e = pair_e[p];
  int tid = threadIdx.x;
  if (tid < CC) m[tid] = mean_raw[p * CC + tid] * (1.f / HWP);
  __syncthreads();
  if (tid < CC) {
    const float* wr = sca_w + (size_t)(e * CC + tid) * CC;
    float acc = sca_b[e * CC + tid];
#pragma unroll 8
    for (int c = 0; c < CC; c++) acc = fmaf(wr[c], m[c], acc);
    sv[tid] = acc;
  }
  __syncthreads();
#pragma unroll
  for (int i = 0; i < 8; i++) {
    int idx = tid + i * 256;
    int o = idx >> 4, k0 = (idx & 15) * 8;
    float bt = beta[e * CC + o];
    const float* src = conv3_w + ((size_t)e * CC + o) * CC + k0;
    ushort* dst = W3eff + ((size_t)pc * CC + o) * CC + k0;
#pragma unroll
    for (int q = 0; q < 8; q++) dst[q] = f2bf(src[q] * sv[k0 + q] * bt);
  }
}

// ---------------- c34: conv3 + residual + LN2 + conv4 + SG fused (xh2 never hits HBM) ----------------
__global__ __launch_bounds__(256, 2) void c34_kernel(
    const ushort* __restrict__ W3eff, const float* __restrict__ b3eff,
    const ushort* __restrict__ W4eff, const float* __restrict__ b4eff,
    const ushort* __restrict__ yT, const ushort* __restrict__ featT,
    const int* __restrict__ pair_e, int pair_lo,
    ushort* __restrict__ x1T, ushort* __restrict__ g5T) {
  __shared__ ushort Ws[CC * CC];
  __shared__ ushort As[CC * CC];
  __shared__ float2 red2[256];
  int pc = blockIdx.z, p = pair_lo + pc, e = pair_e[p];
  int img = p / KT;
  int n0 = blockIdx.x * 128;
  int tid = threadIdx.x, lane = tid & 63, w = tid >> 6;
  int wr = w >> 1, wc = w & 1, fr = lane & 15, kb0 = (lane >> 4) * 16, og = (lane >> 4) * 4;

  stage_tile(W3eff + (size_t)pc * CC * CC, Ws, tid);
  stage_tile(yT + ((size_t)pc * HWP + n0) * CC, As, tid);
  __syncthreads();
  // --- conv3 ---
  f32x4 acc3[4][4] = {};
#pragma unroll
  for (int ks = 0; ks < 4; ks++) {
    bf16x8 a[4], bb[4];
#pragma unroll
    for (int m = 0; m < 4; m++) a[m] = ldfrag(Ws, wr * 64 + m * 16 + fr, ks * 64 + kb0);
#pragma unroll
    for (int n = 0; n < 4; n++) bb[n] = ldfrag(As, wc * 64 + n * 16 + fr, ks * 64 + kb0);
#pragma unroll
    for (int m = 0; m < 4; m++)
#pragma unroll
      for (int n = 0; n < 4; n++)
        acc3[m][n] = __builtin_amdgcn_mfma_f32_16x16x32_bf16(a[m], bb[n], acc3[m][n], 0, 0, 0);
  }
  // --- x1 = feat + acc3 + b3eff; LN2 stats ---
  float s[4] = {}, s2[4] = {};
#pragma unroll
  for (int m = 0; m < 4; m++) {
    int o = wr * 64 + m * 16 + og;
    float4 bvv = *(const float4*)&b3eff[e * CC + o];
#pragma unroll
    for (int n = 0; n < 4; n++) {
      int px = wc * 64 + n * 16 + fr;
      ushort4 f4 = *(const ushort4*)(featT + ((size_t)img * HWP + n0 + px) * CC + o);
      f32x4 v = acc3[m][n];
      v.x += bf2f(f4.x) + bvv.x; v.y += bf2f(f4.y) + bvv.y;
      v.z += bf2f(f4.z) + bvv.z; v.w += bf2f(f4.w) + bvv.w;
      acc3[m][n] = v;
      s[n] += v.x + v.y + v.z + v.w;
      s2[n] += v.x * v.x + v.y * v.y + v.z * v.z + v.w * v.w;
    }
  }
#pragma unroll
  for (int n = 0; n < 4; n++) {
    s[n] += __shfl_xor(s[n], 16, 64); s[n] += __shfl_xor(s[n], 32, 64);
    s2[n] += __shfl_xor(s2[n], 16, 64); s2[n] += __shfl_xor(s2[n], 32, 64);
  }
  if (lane < 16) {
#pragma unroll
    for (int n = 0; n < 4; n++) {
      float2 v; v.x = s[n]; v.y = s2[n];
      red2[wr * 128 + wc * 64 + n * 16 + fr] = v;
    }
  }
  __syncthreads();                 // (A) red2 ready; conv3's Ws/As reads done
  float mu[4], rs[4];
#pragma unroll
  for (int n = 0; n < 4; n++) {
    int px = wc * 64 + n * 16 + fr;
    float2 r0 = red2[px], r1 = red2[128 + px];
    float m_ = (r0.x + r1.x) * (1.f / CC);
    float var = (r0.y + r1.y) * (1.f / CC) - m_ * m_;
    mu[n] = m_; rs[n] = rsqrtf(var + EPSLN);
  }
  // x1 -> Ws (staged), xh2 -> As (staged)
#pragma unroll
  for (int m = 0; m < 4; m++) {
    int o = wr * 64 + m * 16 + og;
#pragma unroll
    for (int n = 0; n < 4; n++) {
      int px = wc * 64 + n * 16 + fr;
      f32x4 v = acc3[m][n];
      stage8(Ws, px, o, pack4(v.x, v.y, v.z, v.w));
      stage8(As, px, o, pack4((v.x - mu[n]) * rs[n], (v.y - mu[n]) * rs[n],
                              (v.z - mu[n]) * rs[n], (v.w - mu[n]) * rs[n]));
    }
  }
  __syncthreads();                 // (B)
  // drain x1 from Ws -> HBM (coalesced)
#pragma unroll
  for (int i = 0; i < 8; i++) {
    int idx = tid + i * 256;
    int px = idx >> 4, ck = idx & 15;
    *(uint4*)((char*)(x1T + ((size_t)pc * HWP + n0 + px) * CC) + ck * 16) = ldstage16(Ws, px, ck);
  }
  __syncthreads();                 // (C) Ws free
  stage_tile(W4eff + (size_t)e * DWC * CC, Ws, tid);
  __syncthreads();                 // (D)
  // --- conv4 half A ---
  f32x4 accA[4][4] = {};
#pragma unroll
  for (int ks = 0; ks < 4; ks++) {
    bf16x8 a[4], bb[4];
#pragma unroll
    for (int m = 0; m < 4; m++) a[m] = ldfrag(Ws, wr * 64 + m * 16 + fr, ks * 64 + kb0);
#pragma unroll
    for (int n = 0; n < 4; n++) bb[n] = ldfrag(As, wc * 64 + n * 16 + fr, ks * 64 + kb0);
#pragma unroll
    for (int m = 0; m < 4; m++)
#pragma unroll
      for (int n = 0; n < 4; n++)
        accA[m][n] = __builtin_amdgcn_mfma_f32_16x16x32_bf16(a[m], bb[n], accA[m][n], 0, 0, 0);
  }
  uint pA[4][4][2];
#pragma unroll
  for (int m = 0; m < 4; m++) {
    int o = wr * 64 + m * 16 + og;
    float4 ba4 = *(const float4*)&b4eff[e * DWC + o];
#pragma unroll
    for (int n = 0; n < 4; n++) {
      f32x4 v = accA[m][n];
      pA[m][n][0] = cvtpk(v.x + ba4.x, v.y + ba4.y);
      pA[m][n][1] = cvtpk(v.z + ba4.z, v.w + ba4.w);
    }
  }
  __syncthreads();                 // (E) Ws(h1) reads done
  stage_tile(W4eff + ((size_t)e * DWC + CC) * CC, Ws, tid);
  __syncthreads();                 // (F)
  // --- conv4 half G ---
  f32x4 accG[4][4] = {};
#pragma unroll
  for (int ks = 0; ks < 4; ks++) {
    bf16x8 a[4], bb[4];
#pragma unroll
    for (int m = 0; m < 4; m++) a[m] = ldfrag(Ws, wr * 64 + m * 16 + fr, ks * 64 + kb0);
#pragma unroll
    for (int n = 0; n < 4; n++) bb[n] = ldfrag(As, wc * 64 + n * 16 + fr, ks * 64 + kb0);
#pragma unroll
    for (int m = 0; m < 4; m++)
#pragma unroll
      for (int n = 0; n < 4; n++)
        accG[m][n] = __builtin_amdgcn_mfma_f32_16x16x32_bf16(a[m], bb[n], accG[m][n], 0, 0, 0);
  }
  __syncthreads();                 // (G) As(xh2) reads done
  // --- SG -> g5 into As ---
#pragma unroll
  for (int m = 0; m < 4; m++) {
    int o = wr * 64 + m * 16 + og;
    float4 bg4 = *(const float4*)&b4eff[e * DWC + CC + o];
#pragma unroll
    for (int n = 0; n < 4; n++) {
      int px = wc * 64 + n * 16 + fr;
      f32x4 vg = accG[m][n];
      uint u0 = pA[m][n][0], u1 = pA[m][n][1];
      float g0 = bf2f((ushort)(u0 & 0xffffu)) * (vg.x + bg4.x);
      float g1 = bf2f((ushort)(u0 >> 16))     * (vg.y + bg4.y);
      float g2 = bf2f((ushort)(u1 & 0xffffu)) * (vg.z + bg4.z);
      float g3 = bf2f((ushort)(u1 >> 16))     * (vg.w + bg4.w);
      stage8(As, px, o, pack4(g0, g1, g2, g3));
    }
  }
  __syncthreads();                 // (H)
#pragma unroll
  for (int i = 0; i < 8; i++) {
    int idx = tid + i * 256;
    int px = idx >> 4, ck = idx & 15;
    *(uint4*)((char*)(g5T + ((size_t)pc * HWP + n0 + px) * CC) + ck * 16) = ldstage16(As, px, ck);
  }
}

// ---------------- conv5: 3-pair accumulated MFMA + transpose epilogue ----------------
__global__ __launch_bounds__(256, 2) void conv5_kernel(
    const ushort* __restrict__ W5eff, const float* __restrict__ b5tot,
    const ushort* __restrict__ g5T, const ushort* __restrict__ x1,
    const float* __restrict__ gate_w, int pair_lo, float* __restrict__ out) {
  __shared__ ushort Ws[CC * CC];
  __shared__ ushort As[CC * CC];
  int sl = blockIdx.z;
  int n0 = blockIdx.x * 128;
  int b = pair_lo / KT + sl;
  int tid = threadIdx.x, lane = tid & 63, w = tid >> 6;
  int wr = w >> 1, wc = w & 1;
  int fr = lane & 15, kb0 = (lane >> 4) * 16, og = (lane >> 4) * 4;
  f32x4 acc[4][4] = {};
  for (int j = 0; j < KT; j++) {
    int pc = sl * KT + j, p = pair_lo + pc;
    __syncthreads();
    stage_tile(W5eff + (size_t)p * CC * CC, Ws, tid);
    stage_tile(g5T + ((size_t)pc * HWP + n0) * CC, As, tid);
    __syncthreads();
#pragma unroll
    for (int ks = 0; ks < 4; ks++) {
      bf16x8 a[4], bfr[4];
#pragma unroll
      for (int m = 0; m < 4; m++) a[m] = ldfrag(Ws, wr * 64 + m * 16 + fr, ks * 64 + kb0);
#pragma unroll
      for (int n = 0; n < 4; n++) bfr[n] = ldfrag(As, wc * 64 + n * 16 + fr, ks * 64 + kb0);
#pragma unroll
      for (int m = 0; m < 4; m++)
#pragma unroll
        for (int n = 0; n < 4; n++)
          acc[m][n] = __builtin_amdgcn_mfma_f32_16x16x32_bf16(a[m], bfr[n], acc[m][n], 0, 0, 0);
    }
  }
  float gw0 = gate_w[pair_lo + sl * KT + 0];
  float gw1 = gate_w[pair_lo + sl * KT + 1];
  float gw2 = gate_w[pair_lo + sl * KT + 2];
  __syncthreads();
  ushort* Ct = As;
#pragma unroll
  for (int m = 0; m < 4; m++) {
    int o = wr * 64 + m * 16 + og;
    float4 bt = *(const float4*)&b5tot[b * CC + o];
#pragma unroll
    for (int n = 0; n < 4; n++) {
      int px = wc * 64 + n * 16 + fr;
      f32x4 v = acc[m][n];
      float r0 = v.x + bt.x, r1 = v.y + bt.y, r2 = v.z + bt.z, r3 = v.w + bt.w;
      size_t xoff = ((size_t)(sl * KT) * HWP + n0 + px) * CC + o;
      ushort4 xa = *(const ushort4*)(x1 + xoff);
      ushort4 xb = *(const ushort4*)(x1 + xoff + (size_t)HWP * CC);
      ushort4 xc = *(const ushort4*)(x1 + xoff + 2 * (size_t)HWP * CC);
      r0 += gw0 * bf2f(xa.x) + gw1 * bf2f(xb.x) + gw2 * bf2f(xc.x);
      r1 += gw0 * bf2f(xa.y) + gw1 * bf2f(xb.y) + gw2 * bf2f(xc.y);
      r2 += gw0 * bf2f(xa.z) + gw1 * bf2f(xb.z) + gw2 * bf2f(xc.z);
      r3 += gw0 * bf2f(xa.w) + gw1 * bf2f(xb.w) + gw2 * bf2f(xc.w);
      *(ushort*)((char*)Ct + (o+0) * 256 + ((px*2) ^ (((o+0) & 7) << 4))) = f2bf1(r0);
      *(ushort*)((char*)Ct + (o+1) * 256 + ((px*2) ^ (((o+1) & 7) << 4))) = f2bf1(r1);
      *(ushort*)((char*)Ct + (o+2) * 256 + ((px*2) ^ (((o+2) & 7) << 4))) = f2bf1(r2);
      *(ushort*)((char*)Ct + (o+3) * 256 + ((px*2) ^ (((o+3) & 7) << 4))) = f2bf1(r3);
    }
  }
  __syncthreads();
  int o = tid >> 1, ph = (tid & 1) * 64;
  float* orow = out + ((size_t)(b * CC + o)) * HWP + n0 + ph;
  int swz = (o & 7) << 4;
#pragma unroll
  for (int i = 0; i < 8; i++) {
    const ushort* lp = (const ushort*)((const char*)Ct + o * 256 + ((ph * 2 + i * 16) ^ swz));
    float4 f0, f1;
    f0.x = bf2f(lp[0]); f0.y = bf2f(lp[1]); f0.z = bf2f(lp[2]); f0.w = bf2f(lp[3]);
    f1.x = bf2f(lp[4]); f1.y = bf2f(lp[5]); f1.z = bf2f(lp[6]); f1.w = bf2f(lp[7]);
    *(float4*)(orow + i * 8) = f0;
    *(float4*)(orow + i * 8 + 4) = f1;
  }
}

extern "C" void kernel_launch(void* const* d_in, const int* in_sizes, int n_in,
                              void* d_out, int out_size, void* d_ws, size_t ws_size,
                              hipStream_t stream) {
  const float* feat    = (const float*)d_in[0];
  const float* weights = (const float*)d_in[1];
  const float* ln1_w   = (const float*)d_in[2];
  const float* ln1_b   = (const float*)d_in[3];
  const float* conv1_w = (const float*)d_in[4];
  const float* conv1_b = (const float*)d_in[5];
  const float* conv2_w = (const float*)d_in[6];
  const float* conv2_b = (const float*)d_in[7];
  const float* sca_w   = (const float*)d_in[8];
  const float* sca_b   = (const float*)d_in[9];
  const float* conv3_w = (const float*)d_in[10];
  const float* conv3_b = (const float*)d_in[11];
  const float* ln2_w   = (const float*)d_in[12];
  const float* ln2_b   = (const float*)d_in[13];
  const float* conv4_w = (const float*)d_in[14];
  const float* conv4_b = (const float*)d_in[15];
  const float* conv5_w = (const float*)d_in[16];
  const float* conv5_b = (const float*)d_in[17];
  const float* beta    = (const float*)d_in[18];
  const float* gamma   = (const float*)d_in[19];

  float* out = (float*)d_out;
  float* out_counts = out + (size_t)BB * CC * HWP;
  float* out_weights = out_counts + EN;

  char* base = (char*)d_ws;
  size_t off = 0;
  auto carveU = [&](size_t n) -> ushort* { ushort* p = (ushort*)(base + off); off += n * 2; return p; };
  auto carveF = [&](size_t n) -> float* { float* p = (float*)(base + off); off += n * 4; return p; };

  ushort* W1eff = carveU((size_t)EN * DWC * CC);
  ushort* W4eff = carveU((size_t)EN * DWC * CC);
  ushort* W5eff = carveU((size_t)NPAIR * CC * CC);
  ushort* W3eff = carveU((size_t)NPAIR * CC * CC);
  float* b1eff  = carveF(EN * DWC);
  float* b4eff  = carveF(EN * DWC);
  float* b3eff  = carveF(EN * CC);
  float* b5tot  = carveF(BB * CC);
  float* gate_w = carveF(64);
  int*   pair_e = (int*)carveF(64);
  float* mean_raw = carveF(NPAIR * CC);
  ushort* xhatT = carveU((size_t)BB * HWP * CC);
  ushort* featT = carveU((size_t)BB * HWP * CC);

  // per-pair: y (1MB) + x1 (1MB) + g5 (1MB)
  const size_t per_pair = (size_t)3 * HWP * CC * 2;
  int ns = 16;
  while (ns > 1 && off + (size_t)ns * KT * per_pair > ws_size) ns >>= 1;
  size_t pr = (size_t)ns * KT;
  ushort* y_T  = carveU(pr * HWP * CC);
  ushort* x1_T = carveU(pr * HWP * CC);
  ushort* g5_T = carveU(pr * HWP * CC);

  gate_kernel<<<1, 256, 0, stream>>>(weights, gate_w, pair_e, out_counts, out_weights, mean_raw);
  fold_kernel<<<13, 256, 0, stream>>>(conv1_w, conv1_b, ln1_w, ln1_b,
                                      conv4_w, conv4_b, ln2_w, ln2_b,
                                      conv3_b, beta, W1eff, b1eff, W4eff, b4eff, b3eff);
  fold2_kernel<<<393, 256, 0, stream>>>(conv5_w, conv5_b, gamma, gate_w, pair_e, W5eff, b5tot);
  ln1_kernel<<<BB * 64, 256, 0, stream>>>(feat, xhatT, featT);

  for (int s0 = 0; s0 < BB; s0 += ns) {
    int np = ns * KT, plo = s0 * KT;
    c1dw_kernel<<<dim3(64, 1, np), 256, 0, stream>>>(W1eff, b1eff, xhatT, conv2_w, conv2_b,
                                                     pair_e, plo, y_T, mean_raw);
    sca_w3fold_kernel<<<np, 256, 0, stream>>>(mean_raw, sca_w, sca_b, conv3_w, beta,
                                              pair_e, plo, W3eff);
    c34_kernel<<<dim3(32, 1, np), 256, 0, stream>>>(W3eff, b3eff, W4eff, b4eff,
                                                    y_T, featT, pair_e, plo, x1_T, g5_T);
    conv5_kernel<<<dim3(32, 1, ns), 256, 0, stream>>>(W5eff, b5tot, g5_T, x1_T,
                                                      gate_w, plo, out);
  }
}

// Round 12
// 185.422 us; speedup vs baseline: 1.8914x; 1.0794x over previous
//
#include <hip/hip_runtime.h>

#define EN 5
#define KT 3
#define BB 16
#define CC 128
#define HWP 4096
#define DWC 256
#define NPAIR 48
#define EPSLN 1e-6f
#define HR 10
#define HPX 100
#define TSTRIDE 106

typedef float f32x4 __attribute__((ext_vector_type(4)));
typedef __bf16 bf16x8 __attribute__((ext_vector_type(8)));

__device__ __forceinline__ float bf2f(ushort u) {
  union { unsigned int u; float f; } v; v.u = ((unsigned int)u) << 16; return v.f;
}
__device__ __forceinline__ uint cvtpk(float lo, float hi) {
  uint r;
  asm("v_cvt_pk_bf16_f32 %0, %1, %2" : "=v"(r) : "v"(lo), "v"(hi));
  return r;
}
__device__ __forceinline__ ushort f2bf(float f) {
  union { float f; unsigned int u; } v; v.f = f;
  unsigned int r = v.u + 0x7FFFu + ((v.u >> 16) & 1u);
  return (ushort)(r >> 16);
}
__device__ __forceinline__ ushort f2bf1(float f) {
  return (ushort)(cvtpk(f, f) & 0xffffu);
}
__device__ __forceinline__ ushort4 pack4(float a, float b, float c, float d) {
  union { uint2 u; ushort4 s; } v;
  v.u.x = cvtpk(a, b);
  v.u.y = cvtpk(c, d);
  return v.s;
}

// ---------------- gate ----------------
__global__ void gate_kernel(const float* __restrict__ weights, float* __restrict__ gate_w,
                            int* __restrict__ pair_e, float* __restrict__ out_counts,
                            float* __restrict__ out_weights, float* __restrict__ mean_raw) {
  __shared__ int sel[NPAIR];
  int tid = threadIdx.x;
  if (tid < BB) {
    float w[EN];
    for (int e = 0; e < EN; e++) w[e] = weights[tid * EN + e];
    int ch[KT]; float cv[KT]; float sum = 0.f;
    for (int j = 0; j < KT; j++) {
      int best = -1; float bv = -3.4e38f;
      for (int e = 0; e < EN; e++) {
        bool used = false;
        for (int q = 0; q < j; q++) if (ch[q] == e) used = true;
        if (!used && w[e] > bv) { bv = w[e]; best = e; }
      }
      ch[j] = best; cv[j] = bv; sum += bv;
    }
    float inv = 1.f / sum;
    for (int j = 0; j < KT; j++) {
      gate_w[tid * KT + j] = cv[j] * inv;
      pair_e[tid * KT + j] = ch[j];
      sel[tid * KT + j] = ch[j];
    }
  }
  for (int i = tid; i < NPAIR * CC; i += 256) mean_raw[i] = 0.f;
  __syncthreads();
  if (tid < EN) {
    int cnt = 0;
    for (int i = 0; i < NPAIR; i++) if (sel[i] == tid) cnt++;
    out_counts[tid] = (float)cnt;
  }
  if (tid < BB * EN) out_weights[tid] = weights[tid];
}

// ---------------- fold LN into conv1/conv4 ----------------
__global__ void fold_kernel(const float* __restrict__ conv1_w, const float* __restrict__ conv1_b,
                            const float* __restrict__ ln1_w, const float* __restrict__ ln1_b,
                            const float* __restrict__ conv4_w, const float* __restrict__ conv4_b,
                            const float* __restrict__ ln2_w, const float* __restrict__ ln2_b,
                            const float* __restrict__ conv3_b, const float* __restrict__ beta,
                            ushort* __restrict__ W1eff, float* __restrict__ b1eff,
                            ushort* __restrict__ W4eff, float* __restrict__ b4eff,
                            float* __restrict__ b3eff) {
  int gid = blockIdx.x * 256 + threadIdx.x;
  if (gid < 2 * EN * DWC) {
    int which = gid / (EN * DWC), rem = gid % (EN * DWC);
    int e = rem / DWC, o = rem % DWC;
    const float* src = (which ? conv4_w : conv1_w) + (size_t)(e * DWC + o) * CC;
    const float* lw = (which ? ln2_w : ln1_w) + e * CC;
    const float* lb = (which ? ln2_b : ln1_b) + e * CC;
    float bacc = (which ? conv4_b : conv1_b)[e * DWC + o];
    ushort* dst = (which ? W4eff : W1eff) + (size_t)(e * DWC + o) * CC;
    for (int c = 0; c < CC; c++) {
      float wv = src[c];
      dst[c] = f2bf(wv * lw[c]);
      bacc += wv * lb[c];
    }
    (which ? b4eff : b1eff)[e * DWC + o] = bacc;
  } else if (gid < 2 * EN * DWC + EN * CC) {
    int x = gid - 2 * EN * DWC;
    b3eff[x] = beta[x] * conv3_b[x];
  }
}

// ---------------- fold2: W5eff[p]=conv5_w[e]*gamma*gate; b5tot ----------------
__global__ void fold2_kernel(const float* __restrict__ conv5_w, const float* __restrict__ conv5_b,
                             const float* __restrict__ gamma, const float* __restrict__ gate_w,
                             const int* __restrict__ pair_e,
                             ushort* __restrict__ W5eff, float* __restrict__ b5tot) {
  int gid = blockIdx.x * 256 + threadIdx.x;
  const int nW = NPAIR * CC * CC / 8;
  if (gid < nW) {
    int base = gid * 8;
    int p = base >> 14, rem = base & 16383;
    int o = rem >> 7, k0 = rem & 127;
    int e = pair_e[p];
    float sc = gamma[e * CC + o] * gate_w[p];
    const float* src = conv5_w + ((size_t)e * CC + o) * CC + k0;
    ushort* dst = W5eff + ((size_t)p * CC + o) * CC + k0;
    for (int q = 0; q < 8; q++) dst[q] = f2bf(src[q] * sc);
  } else if (gid < nW + BB * CC) {
    int x = gid - nW;
    int b = x >> 7, o = x & 127;
    float s = 0.f;
    for (int j = 0; j < KT; j++) {
      int p = b * KT + j, e = pair_e[p];
      s += gate_w[p] * gamma[e * CC + o] * conv5_b[e * CC + o];
    }
    b5tot[x] = s;
  }
}

// ---------------- LN1 + transpose ----------------
__global__ __launch_bounds__(256) void ln1_kernel(const float* __restrict__ feat,
                                                  ushort* __restrict__ xhatT,
                                                  ushort* __restrict__ featT) {
  __shared__ float tile[CC * 64];
  __shared__ float pS[4][64], pS2[4][64], bcM[64], bcR[64];
  int bimg = blockIdx.x >> 6;
  int n0 = (blockIdx.x & 63) * 64;
  int tid = threadIdx.x;
  const float* src = feat + (size_t)bimg * CC * HWP + n0;
#pragma unroll
  for (int i = 0; i < 8; i++) {
    int ch = tid + i * 256;
    int row = ch >> 4, c16 = ch & 15;
    *(float4*)&tile[row * 64 + c16 * 4] = *(const float4*)(src + (size_t)row * HWP + c16 * 4);
  }
  __syncthreads();
  int lane = tid & 63, w = tid >> 6;
  float s = 0.f, s2 = 0.f;
#pragma unroll
  for (int i = 0; i < 32; i++) {
    float v = tile[(w * 32 + i) * 64 + lane];
    s += v; s2 += v * v;
  }
  pS[w][lane] = s; pS2[w][lane] = s2;
  __syncthreads();
  if (w == 0) {
    float t1 = pS[0][lane] + pS[1][lane] + pS[2][lane] + pS[3][lane];
    float t2 = pS2[0][lane] + pS2[1][lane] + pS2[2][lane] + pS2[3][lane];
    float mu = t1 * (1.f / CC);
    float var = t2 * (1.f / CC) - mu * mu;
    bcM[lane] = mu; bcR[lane] = rsqrtf(var + EPSLN);
  }
  __syncthreads();
  float mu = bcM[lane], r = bcR[lane];
  size_t obase = ((size_t)bimg * HWP + n0 + lane) * CC + w * 32;
#pragma unroll
  for (int i = 0; i < 4; i++) {
    float v[8];
#pragma unroll
    for (int q = 0; q < 8; q++) v[q] = tile[(w * 32 + i * 8 + q) * 64 + lane];
    *(ushort4*)(featT + obase + i * 8)     = pack4(v[0], v[1], v[2], v[3]);
    *(ushort4*)(featT + obase + i * 8 + 4) = pack4(v[4], v[5], v[6], v[7]);
    *(ushort4*)(xhatT + obase + i * 8)     = pack4((v[0]-mu)*r, (v[1]-mu)*r, (v[2]-mu)*r, (v[3]-mu)*r);
    *(ushort4*)(xhatT + obase + i * 8 + 4) = pack4((v[4]-mu)*r, (v[5]-mu)*r, (v[6]-mu)*r, (v[7]-mu)*r);
  }
}

// ---------------- shared helpers ----------------
__device__ __forceinline__ void stage_tile(const ushort* __restrict__ g, ushort* lds, int tid) {
#pragma unroll
  for (int i = 0; i < 8; i++) {
    int d = (tid + i * 256) * 16;
    int row = d >> 8;
    uint4 v = *(const uint4*)((const char*)g + d);
    *(uint4*)((char*)lds + (d ^ ((row & 7) << 4))) = v;
  }
}
__device__ __forceinline__ bf16x8 ldfrag(const ushort* lds, int row, int kb) {
  return *(const bf16x8*)((const char*)lds + row * 256 + (kb ^ ((row & 7) << 4)));
}
__device__ __forceinline__ void stage8(ushort* st, int px, int o, ushort4 v) {
  *(ushort4*)((char*)st + px * 256 + ((o * 2) ^ ((px & 7) << 4))) = v;
}
__device__ __forceinline__ uint4 ldstage16(const ushort* st, int px, int ck) {
  return *(const uint4*)((const char*)st + px * 256 + ((ck * 16) ^ ((px & 7) << 4)));
}

// ---------------- fused conv1 + depthwise3x3 + SimpleGate + mean (v4: ch-half split) ----------------
// Block = (8x8 tile, ch-half h, pair). Computes t-ch [h*64,h*64+64) u [128+h*64, +64),
// i.e. exactly the (a,g) pairs for SG outputs [h*64, h*64+64). LDS ~27KB -> ~6 blocks/CU.
__global__ __launch_bounds__(256, 4) void c1dw_kernel(
    const ushort* __restrict__ W1eff, const float* __restrict__ b1eff,
    const ushort* __restrict__ xhatT,
    const float* __restrict__ conv2_w, const float* __restrict__ conv2_b,
    const int* __restrict__ pair_e, int pair_lo,
    ushort* __restrict__ yT, float* __restrict__ mean_raw) {
  __shared__ __align__(16) char smem[CC * TSTRIDE * 2];   // 27136 B: halo(25.6K) / Th(27.1K) / ystage+psum
  int ts = blockIdx.x;
  int h = blockIdx.y;
  int pc = blockIdx.z, p = pair_lo + pc, e = pair_e[p];
  int img = p / KT;
  int th = (ts >> 3) * 8, tw = (ts & 7) * 8;
  int tid = threadIdx.x, lane = tid & 63, w = tid >> 6;
  int fr = lane & 15, qf = lane >> 4;

  // phase 1: stage full xhat halo (256B rows, swizzled)
#pragma unroll
  for (int i = 0; i < 7; i++) {
    int idx = tid + i * 256;
    if (idx < HPX * 16) {
      int r = idx >> 4, seg = idx & 15;
      int hy = r / HR, hx = r - hy * HR;
      int hh = th + hy - 1, ww = tw + hx - 1;
      int hc = min(max(hh, 0), 63), wc = min(max(ww, 0), 63);
      uint4 v = *(const uint4*)(xhatT + ((size_t)img * HWP + hc * 64 + wc) * CC + seg * 8);
      *(uint4*)(smem + r * 256 + ((seg * 16) ^ ((r & 7) << 4))) = v;
    }
  }
  __syncthreads();

  // phase 2: MFMA conv1 for this half's 128 t-channels.
  // wave 0,1 -> a-half (t-ch h*64 + w*32 ..); wave 2,3 -> g-half (t-ch 128 + h*64 + (w&1)*32 ..)
  int gchbase = ((w >> 1) * CC) + h * 64 + (w & 1) * 32;   // global t-channel base
  int lcbase  = ((w >> 1) * 64) + (w & 1) * 32;            // local Th channel base
  f32x4 acc[7][2] = {};
#pragma unroll
  for (int ks = 0; ks < 4; ks++) {
    bf16x8 bfr[2];
#pragma unroll
    for (int mf = 0; mf < 2; mf++)
      bfr[mf] = *(const bf16x8*)(W1eff + (size_t)(e * DWC + gchbase + mf * 16 + fr) * CC + ks * 32 + qf * 8);
#pragma unroll
    for (int nf = 0; nf < 7; nf++) {
      bf16x8 a = ldfrag((const ushort*)smem, nf * 16 + fr, ks * 64 + qf * 16);
#pragma unroll
      for (int mf = 0; mf < 2; mf++)
        acc[nf][mf] = __builtin_amdgcn_mfma_f32_16x16x32_bf16(a, bfr[mf], acc[nf][mf], 0, 0, 0);
    }
  }
  float bias[2];
#pragma unroll
  for (int mf = 0; mf < 2; mf++) bias[mf] = b1eff[e * DWC + gchbase + mf * 16 + fr];
  __syncthreads();   // halo reads done; smem becomes channel-major Th [128][TSTRIDE]

  // phase 3: t -> Th[lc][px], vectorized u32 stores
  ushort* Th = (ushort*)smem;
  int px0q = qf * 4;
#pragma unroll
  for (int nf = 0; nf < 7; nf++) {
    int px = nf * 16 + px0q;
    if (px < HPX) {
#pragma unroll
      for (int mf = 0; mf < 2; mf++) {
        int lc = lcbase + mf * 16 + fr;
        f32x4 v = acc[nf][mf];
        float bb = bias[mf];
        uint u0 = cvtpk(v.x + bb, v.y + bb);
        uint u1 = cvtpk(v.z + bb, v.w + bb);
        ushort* dst = Th + lc * TSTRIDE + px;
        *(uint*)dst = u0;
        *(uint*)(dst + 2) = u1;
      }
    }
  }
  __syncthreads();

  // phase 4: depthwise 3x3 + SG. thread = (cp 0..63 SG-channel, quarter q = wave -> 2 out rows)
  int cp = lane, q = w;
  bool zT = (th == 0), zB = (th == 56);
  bool leftE = (tw == 0), rightE = (tw == 56);
  int sgch = h * 64 + cp;
  const float* wAp = conv2_w + ((size_t)e * DWC + sgch) * 9;
  const float* wGp = conv2_w + ((size_t)(e * DWC + CC) + sgch) * 9;
  float wA9[9], wG9[9];
#pragma unroll
  for (int k = 0; k < 9; k++) { wA9[k] = wAp[k]; wG9[k] = wGp[k]; }
  float ba = conv2_b[e * DWC + sgch], bg = conv2_b[e * DWC + CC + sgch];

  auto loadrowz = [&](float* dst, const ushort* pp, bool zrow) {
    if (zrow) {
#pragma unroll
      for (int qq = 0; qq < 10; qq++) dst[qq] = 0.f;
    } else {
#pragma unroll
      for (int qq = 0; qq < 5; qq++) {
        uint u = *(const uint*)(pp + qq * 2);
        dst[qq * 2]     = bf2f((ushort)(u & 0xffffu));
        dst[qq * 2 + 1] = bf2f((ushort)(u >> 16));
      }
      if (leftE) dst[0] = 0.f;
      if (rightE) dst[9] = 0.f;
    }
  };
  auto comp3 = [&](const float* w9, const float* r0, const float* r1, const float* r2, float* out) {
#pragma unroll
    for (int ox = 0; ox < 8; ox++) {
      float a = r0[ox] * w9[0];
      a = fmaf(r0[ox + 1], w9[1], a); a = fmaf(r0[ox + 2], w9[2], a);
      a = fmaf(r1[ox],     w9[3], a); a = fmaf(r1[ox + 1], w9[4], a);
      a = fmaf(r1[ox + 2], w9[5], a);
      a = fmaf(r2[ox],     w9[6], a); a = fmaf(r2[ox + 1], w9[7], a);
      a = fmaf(r2[ox + 2], w9[8], a);
      out[ox] = a;
    }
  };

  float win[3][10];
  float outA[2][8], outG[2][8];
  {
    const ushort* rA = Th + cp * TSTRIDE + q * 20;          // halo rows 2q..2q+3
    loadrowz(win[0], rA, (q == 0) && zT);
    loadrowz(win[1], rA + 10, false);
    loadrowz(win[2], rA + 20, false);
    comp3(wA9, win[0], win[1], win[2], outA[0]);
    loadrowz(win[0], rA + 30, (q == 3) && zB);
    comp3(wA9, win[1], win[2], win[0], outA[1]);
  }
  {
    const ushort* rG = Th + (64 + cp) * TSTRIDE + q * 20;
    loadrowz(win[0], rG, (q == 0) && zT);
    loadrowz(win[1], rG + 10, false);
    loadrowz(win[2], rG + 20, false);
    comp3(wG9, win[0], win[1], win[2], outG[0]);
    loadrowz(win[0], rG + 30, (q == 3) && zB);
    comp3(wG9, win[1], win[2], win[0], outG[1]);
  }
  uint ypk[8];
  float csum = 0.f;
#pragma unroll
  for (int r = 0; r < 2; r++)
#pragma unroll
    for (int ox = 0; ox < 8; ox += 2) {
      float y0 = (outA[r][ox]     + ba) * (outG[r][ox]     + bg);
      float y1 = (outA[r][ox + 1] + ba) * (outG[r][ox + 1] + bg);
      csum += y0 + y1;
      ypk[r * 4 + (ox >> 1)] = cvtpk(y0, y1);
    }
  __syncthreads();   // Th reads done; smem becomes ystage(8K) + psum(1K)

  // phase 5: ystage scatter (128B rows, swizzled), psum, coalesced drain + mean
  float* psum = (float*)(smem + 8192);
#pragma unroll
  for (int r = 0; r < 2; r++)
#pragma unroll
    for (int ox = 0; ox < 8; ox++) {
      int opx = (q * 2 + r) * 8 + ox;
      uint pkv = ypk[r * 4 + (ox >> 1)];
      ushort val = (ox & 1) ? (ushort)(pkv >> 16) : (ushort)(pkv & 0xffffu);
      *(ushort*)(smem + opx * 128 + ((cp * 2) ^ ((opx & 7) << 4))) = val;
    }
  psum[tid] = csum;
  __syncthreads();
#pragma unroll
  for (int i = 0; i < 2; i++) {
    int idx = tid + i * 256;
    int opx = idx >> 3, ck = idx & 7;
    uint4 v = *(const uint4*)(smem + opx * 128 + ((ck * 16) ^ ((opx & 7) << 4)));
    int n = (th + (opx >> 3)) * 64 + tw + (opx & 7);
    *(uint4*)((char*)(yT + ((size_t)pc * HWP + n) * CC + h * 64) + ck * 16) = v;
  }
  if (tid < 64) {
    float s = psum[tid] + psum[64 + tid] + psum[128 + tid] + psum[192 + tid];
    atomicAdd(&mean_raw[p * CC + h * 64 + tid], s);
  }
}

// ---------------- SCA + W3eff fold merged ----------------
__global__ void sca_w3fold_kernel(const float* __restrict__ mean_raw,
                                  const float* __restrict__ sca_w, const float* __restrict__ sca_b,
                                  const float* __restrict__ conv3_w, const float* __restrict__ beta,
                                  const int* __restrict__ pair_e, int pair_lo,
                                  ushort* __restrict__ W3eff) {
  __shared__ float m[CC];
  __shared__ float sv[CC];
  int pc = blockIdx.x, p = pair_lo + pc, e = pair_e[p];
  int tid = threadIdx.x;
  if (tid < CC) m[tid] = mean_raw[p * CC + tid] * (1.f / HWP);
  __syncthreads();
  if (tid < CC) {
    const float* wr = sca_w + (size_t)(e * CC + tid) * CC;
    float acc = sca_b[e * CC + tid];
#pragma unroll 8
    for (int c = 0; c < CC; c++) acc = fmaf(wr[c], m[c], acc);
    sv[tid] = acc;
  }
  __syncthreads();
#pragma unroll
  for (int i = 0; i < 8; i++) {
    int idx = tid + i * 256;
    int o = idx >> 4, k0 = (idx & 15) * 8;
    float bt = beta[e * CC + o];
    const float* src = conv3_w + ((size_t)e * CC + o) * CC + k0;
    ushort* dst = W3eff + ((size_t)pc * CC + o) * CC + k0;
#pragma unroll
    for (int q = 0; q < 8; q++) dst[q] = f2bf(src[q] * sv[k0 + q] * bt);
  }
}

// ---------------- c34: conv3 + residual + LN2 + conv4 + SG fused ----------------
__global__ __launch_bounds__(256, 2) void c34_kernel(
    const ushort* __restrict__ W3eff, const float* __restrict__ b3eff,
    const ushort* __restrict__ W4eff, const float* __restrict__ b4eff,
    const ushort* __restrict__ yT, const ushort* __restrict__ featT,
    const int* __restrict__ pair_e, int pair_lo,
    ushort* __restrict__ x1T, ushort* __restrict__ g5T) {
  __shared__ ushort Ws[CC * CC];
  __shared__ ushort As[CC * CC];
  __shared__ float2 red2[256];
  int pc = blockIdx.z, p = pair_lo + pc, e = pair_e[p];
  int img = p / KT;
  int n0 = blockIdx.x * 128;
  int tid = threadIdx.x, lane = tid & 63, w = tid >> 6;
  int wr = w >> 1, wc = w & 1, fr = lane & 15, kb0 = (lane >> 4) * 16, og = (lane >> 4) * 4;

  stage_tile(W3eff + (size_t)pc * CC * CC, Ws, tid);
  stage_tile(yT + ((size_t)pc * HWP + n0) * CC, As, tid);
  __syncthreads();
  f32x4 acc3[4][4] = {};
#pragma unroll
  for (int ks = 0; ks < 4; ks++) {
    bf16x8 a[4], bb[4];
#pragma unroll
    for (int m = 0; m < 4; m++) a[m] = ldfrag(Ws, wr * 64 + m * 16 + fr, ks * 64 + kb0);
#pragma unroll
    for (int n = 0; n < 4; n++) bb[n] = ldfrag(As, wc * 64 + n * 16 + fr, ks * 64 + kb0);
#pragma unroll
    for (int m = 0; m < 4; m++)
#pragma unroll
      for (int n = 0; n < 4; n++)
        acc3[m][n] = __builtin_amdgcn_mfma_f32_16x16x32_bf16(a[m], bb[n], acc3[m][n], 0, 0, 0);
  }
  float s[4] = {}, s2[4] = {};
#pragma unroll
  for (int m = 0; m < 4; m++) {
    int o = wr * 64 + m * 16 + og;
    float4 bvv = *(const float4*)&b3eff[e * CC + o];
#pragma unroll
    for (int n = 0; n < 4; n++) {
      int px = wc * 64 + n * 16 + fr;
      ushort4 f4 = *(const ushort4*)(featT + ((size_t)img * HWP + n0 + px) * CC + o);
      f32x4 v = acc3[m][n];
      v.x += bf2f(f4.x) + bvv.x; v.y += bf2f(f4.y) + bvv.y;
      v.z += bf2f(f4.z) + bvv.z; v.w += bf2f(f4.w) + bvv.w;
      acc3[m][n] = v;
      s[n] += v.x + v.y + v.z + v.w;
      s2[n] += v.x * v.x + v.y * v.y + v.z * v.z + v.w * v.w;
    }
  }
#pragma unroll
  for (int n = 0; n < 4; n++) {
    s[n] += __shfl_xor(s[n], 16, 64); s[n] += __shfl_xor(s[n], 32, 64);
    s2[n] += __shfl_xor(s2[n], 16, 64); s2[n] += __shfl_xor(s2[n], 32, 64);
  }
  if (lane < 16) {
#pragma unroll
    for (int n = 0; n < 4; n++) {
      float2 v; v.x = s[n]; v.y = s2[n];
      red2[wr * 128 + wc * 64 + n * 16 + fr] = v;
    }
  }
  __syncthreads();
  float mu[4], rs[4];
#pragma unroll
  for (int n = 0; n < 4; n++) {
    int px = wc * 64 + n * 16 + fr;
    float2 r0 = red2[px], r1 = red2[128 + px];
    float m_ = (r0.x + r1.x) * (1.f / CC);
    float var = (r0.y + r1.y) * (1.f / CC) - m_ * m_;
    mu[n] = m_; rs[n] = rsqrtf(var + EPSLN);
  }
#pragma unroll
  for (int m = 0; m < 4; m++) {
    int o = wr * 64 + m * 16 + og;
#pragma unroll
    for (int n = 0; n < 4; n++) {
      int px = wc * 64 + n * 16 + fr;
      f32x4 v = acc3[m][n];
      stage8(Ws, px, o, pack4(v.x, v.y, v.z, v.w));
      stage8(As, px, o, pack4((v.x - mu[n]) * rs[n], (v.y - mu[n]) * rs[n],
                              (v.z - mu[n]) * rs[n], (v.w - mu[n]) * rs[n]));
    }
  }
  __syncthreads();
#pragma unroll
  for (int i = 0; i < 8; i++) {
    int idx = tid + i * 256;
    int px = idx >> 4, ck = idx & 15;
    *(uint4*)((char*)(x1T + ((size_t)pc * HWP + n0 + px) * CC) + ck * 16) = ldstage16(Ws, px, ck);
  }
  __syncthreads();
  stage_tile(W4eff + (size_t)e * DWC * CC, Ws, tid);
  __syncthreads();
  f32x4 accA[4][4] = {};
#pragma unroll
  for (int ks = 0; ks < 4; ks++) {
    bf16x8 a[4], bb[4];
#pragma unroll
    for (int m = 0; m < 4; m++) a[m] = ldfrag(Ws, wr * 64 + m * 16 + fr, ks * 64 + kb0);
#pragma unroll
    for (int n = 0; n < 4; n++) bb[n] = ldfrag(As, wc * 64 + n * 16 + fr, ks * 64 + kb0);
#pragma unroll
    for (int m = 0; m < 4; m++)
#pragma unroll
      for (int n = 0; n < 4; n++)
        accA[m][n] = __builtin_amdgcn_mfma_f32_16x16x32_bf16(a[m], bb[n], accA[m][n], 0, 0, 0);
  }
  uint pA[4][4][2];
#pragma unroll
  for (int m = 0; m < 4; m++) {
    int o = wr * 64 + m * 16 + og;
    float4 ba4 = *(const float4*)&b4eff[e * DWC + o];
#pragma unroll
    for (int n = 0; n < 4; n++) {
      f32x4 v = accA[m][n];
      pA[m][n][0] = cvtpk(v.x + ba4.x, v.y + ba4.y);
      pA[m][n][1] = cvtpk(v.z + ba4.z, v.w + ba4.w);
    }
  }
  __syncthreads();
  stage_tile(W4eff + ((size_t)e * DWC + CC) * CC, Ws, tid);
  __syncthreads();
  f32x4 accG[4][4] = {};
#pragma unroll
  for (int ks = 0; ks < 4; ks++) {
    bf16x8 a[4], bb[4];
#pragma unroll
    for (int m = 0; m < 4; m++) a[m] = ldfrag(Ws, wr * 64 + m * 16 + fr, ks * 64 + kb0);
#pragma unroll
    for (int n = 0; n < 4; n++) bb[n] = ldfrag(As, wc * 64 + n * 16 + fr, ks * 64 + kb0);
#pragma unroll
    for (int m = 0; m < 4; m++)
#pragma unroll
      for (int n = 0; n < 4; n++)
        accG[m][n] = __builtin_amdgcn_mfma_f32_16x16x32_bf16(a[m], bb[n], accG[m][n], 0, 0, 0);
  }
  __syncthreads();
#pragma unroll
  for (int m = 0; m < 4; m++) {
    int o = wr * 64 + m * 16 + og;
    float4 bg4 = *(const float4*)&b4eff[e * DWC + CC + o];
#pragma unroll
    for (int n = 0; n < 4; n++) {
      int px = wc * 64 + n * 16 + fr;
      f32x4 vg = accG[m][n];
      uint u0 = pA[m][n][0], u1 = pA[m][n][1];
      float g0 = bf2f((ushort)(u0 & 0xffffu)) * (vg.x + bg4.x);
      float g1 = bf2f((ushort)(u0 >> 16))     * (vg.y + bg4.y);
      float g2 = bf2f((ushort)(u1 & 0xffffu)) * (vg.z + bg4.z);
      float g3 = bf2f((ushort)(u1 >> 16))     * (vg.w + bg4.w);
      stage8(As, px, o, pack4(g0, g1, g2, g3));
    }
  }
  __syncthreads();
#pragma unroll
  for (int i = 0; i < 8; i++) {
    int idx = tid + i * 256;
    int px = idx >> 4, ck = idx & 15;
    *(uint4*)((char*)(g5T + ((size_t)pc * HWP + n0 + px) * CC) + ck * 16) = ldstage16(As, px, ck);
  }
}

// ---------------- conv5: 3-pair accumulated MFMA + transpose epilogue ----------------
__global__ __launch_bounds__(256, 2) void conv5_kernel(
    const ushort* __restrict__ W5eff, const float* __restrict__ b5tot,
    const ushort* __restrict__ g5T, const ushort* __restrict__ x1,
    const float* __restrict__ gate_w, int pair_lo, float* __restrict__ out) {
  __shared__ ushort Ws[CC * CC];
  __shared__ ushort As[CC * CC];
  int sl = blockIdx.z;
  int n0 = blockIdx.x * 128;
  int b = pair_lo / KT + sl;
  int tid = threadIdx.x, lane = tid & 63, w = tid >> 6;
  int wr = w >> 1, wc = w & 1;
  int fr = lane & 15, kb0 = (lane >> 4) * 16, og = (lane >> 4) * 4;
  f32x4 acc[4][4] = {};
  for (int j = 0; j < KT; j++) {
    int pc = sl * KT + j, p = pair_lo + pc;
    __syncthreads();
    stage_tile(W5eff + (size_t)p * CC * CC, Ws, tid);
    stage_tile(g5T + ((size_t)pc * HWP + n0) * CC, As, tid);
    __syncthreads();
#pragma unroll
    for (int ks = 0; ks < 4; ks++) {
      bf16x8 a[4], bfr[4];
#pragma unroll
      for (int m = 0; m < 4; m++) a[m] = ldfrag(Ws, wr * 64 + m * 16 + fr, ks * 64 + kb0);
#pragma unroll
      for (int n = 0; n < 4; n++) bfr[n] = ldfrag(As, wc * 64 + n * 16 + fr, ks * 64 + kb0);
#pragma unroll
      for (int m = 0; m < 4; m++)
#pragma unroll
        for (int n = 0; n < 4; n++)
          acc[m][n] = __builtin_amdgcn_mfma_f32_16x16x32_bf16(a[m], bfr[n], acc[m][n], 0, 0, 0);
    }
  }
  float gw0 = gate_w[pair_lo + sl * KT + 0];
  float gw1 = gate_w[pair_lo + sl * KT + 1];
  float gw2 = gate_w[pair_lo + sl * KT + 2];
  __syncthreads();
  ushort* Ct = As;
#pragma unroll
  for (int m = 0; m < 4; m++) {
    int o = wr * 64 + m * 16 + og;
    float4 bt = *(const float4*)&b5tot[b * CC + o];
#pragma unroll
    for (int n = 0; n < 4; n++) {
      int px = wc * 64 + n * 16 + fr;
      f32x4 v = acc[m][n];
      float r0 = v.x + bt.x, r1 = v.y + bt.y, r2 = v.z + bt.z, r3 = v.w + bt.w;
      size_t xoff = ((size_t)(sl * KT) * HWP + n0 + px) * CC + o;
      ushort4 xa = *(const ushort4*)(x1 + xoff);
      ushort4 xb = *(const ushort4*)(x1 + xoff + (size_t)HWP * CC);
      ushort4 xc = *(const ushort4*)(x1 + xoff + 2 * (size_t)HWP * CC);
      r0 += gw0 * bf2f(xa.x) + gw1 * bf2f(xb.x) + gw2 * bf2f(xc.x);
      r1 += gw0 * bf2f(xa.y) + gw1 * bf2f(xb.y) + gw2 * bf2f(xc.y);
      r2 += gw0 * bf2f(xa.z) + gw1 * bf2f(xb.z) + gw2 * bf2f(xc.z);
      r3 += gw0 * bf2f(xa.w) + gw1 * bf2f(xb.w) + gw2 * bf2f(xc.w);
      *(ushort*)((char*)Ct + (o+0) * 256 + ((px*2) ^ (((o+0) & 7) << 4))) = f2bf1(r0);
      *(ushort*)((char*)Ct + (o+1) * 256 + ((px*2) ^ (((o+1) & 7) << 4))) = f2bf1(r1);
      *(ushort*)((char*)Ct + (o+2) * 256 + ((px*2) ^ (((o+2) & 7) << 4))) = f2bf1(r2);
      *(ushort*)((char*)Ct + (o+3) * 256 + ((px*2) ^ (((o+3) & 7) << 4))) = f2bf1(r3);
    }
  }
  __syncthreads();
  int o = tid >> 1, ph = (tid & 1) * 64;
  float* orow = out + ((size_t)(b * CC + o)) * HWP + n0 + ph;
  int swz = (o & 7) << 4;
#pragma unroll
  for (int i = 0; i < 8; i++) {
    const ushort* lp = (const ushort*)((const char*)Ct + o * 256 + ((ph * 2 + i * 16) ^ swz));
    float4 f0, f1;
    f0.x = bf2f(lp[0]); f0.y = bf2f(lp[1]); f0.z = bf2f(lp[2]); f0.w = bf2f(lp[3]);
    f1.x = bf2f(lp[4]); f1.y = bf2f(lp[5]); f1.z = bf2f(lp[6]); f1.w = bf2f(lp[7]);
    *(float4*)(orow + i * 8) = f0;
    *(float4*)(orow + i * 8 + 4) = f1;
  }
}

extern "C" void kernel_launch(void* const* d_in, const int* in_sizes, int n_in,
                              void* d_out, int out_size, void* d_ws, size_t ws_size,
                              hipStream_t stream) {
  const float* feat    = (const float*)d_in[0];
  const float* weights = (const float*)d_in[1];
  const float* ln1_w   = (const float*)d_in[2];
  const float* ln1_b   = (const float*)d_in[3];
  const float* conv1_w = (const float*)d_in[4];
  const float* conv1_b = (const float*)d_in[5];
  const float* conv2_w = (const float*)d_in[6];
  const float* conv2_b = (const float*)d_in[7];
  const float* sca_w   = (const float*)d_in[8];
  const float* sca_b   = (const float*)d_in[9];
  const float* conv3_w = (const float*)d_in[10];
  const float* conv3_b = (const float*)d_in[11];
  const float* ln2_w   = (const float*)d_in[12];
  const float* ln2_b   = (const float*)d_in[13];
  const float* conv4_w = (const float*)d_in[14];
  const float* conv4_b = (const float*)d_in[15];
  const float* conv5_w = (const float*)d_in[16];
  const float* conv5_b = (const float*)d_in[17];
  const float* beta    = (const float*)d_in[18];
  const float* gamma   = (const float*)d_in[19];

  float* out = (float*)d_out;
  float* out_counts = out + (size_t)BB * CC * HWP;
  float* out_weights = out_counts + EN;

  char* base = (char*)d_ws;
  size_t off = 0;
  auto carveU = [&](size_t n) -> ushort* { ushort* p = (ushort*)(base + off); off += n * 2; return p; };
  auto carveF = [&](size_t n) -> float* { float* p = (float*)(base + off); off += n * 4; return p; };

  ushort* W1eff = carveU((size_t)EN * DWC * CC);
  ushort* W4eff = carveU((size_t)EN * DWC * CC);
  ushort* W5eff = carveU((size_t)NPAIR * CC * CC);
  ushort* W3eff = carveU((size_t)NPAIR * CC * CC);
  float* b1eff  = carveF(EN * DWC);
  float* b4eff  = carveF(EN * DWC);
  float* b3eff  = carveF(EN * CC);
  float* b5tot  = carveF(BB * CC);
  float* gate_w = carveF(64);
  int*   pair_e = (int*)carveF(64);
  float* mean_raw = carveF(NPAIR * CC);
  ushort* xhatT = carveU((size_t)BB * HWP * CC);
  ushort* featT = carveU((size_t)BB * HWP * CC);

  // per-pair: y (1MB) + x1 (1MB) + g5 (1MB)
  const size_t per_pair = (size_t)3 * HWP * CC * 2;
  int ns = 16;
  while (ns > 1 && off + (size_t)ns * KT * per_pair > ws_size) ns >>= 1;
  size_t pr = (size_t)ns * KT;
  ushort* y_T  = carveU(pr * HWP * CC);
  ushort* x1_T = carveU(pr * HWP * CC);
  ushort* g5_T = carveU(pr * HWP * CC);

  gate_kernel<<<1, 256, 0, stream>>>(weights, gate_w, pair_e, out_counts, out_weights, mean_raw);
  fold_kernel<<<13, 256, 0, stream>>>(conv1_w, conv1_b, ln1_w, ln1_b,
                                      conv4_w, conv4_b, ln2_w, ln2_b,
                                      conv3_b, beta, W1eff, b1eff, W4eff, b4eff, b3eff);
  fold2_kernel<<<393, 256, 0, stream>>>(conv5_w, conv5_b, gamma, gate_w, pair_e, W5eff, b5tot);
  ln1_kernel<<<BB * 64, 256, 0, stream>>>(feat, xhatT, featT);

  for (int s0 = 0; s0 < BB; s0 += ns) {
    int np = ns * KT, plo = s0 * KT;
    c1dw_kernel<<<dim3(64, 2, np), 256, 0, stream>>>(W1eff, b1eff, xhatT, conv2_w, conv2_b,
                                                     pair_e, plo, y_T, mean_raw);
    sca_w3fold_kernel<<<np, 256, 0, stream>>>(mean_raw, sca_w, sca_b, conv3_w, beta,
                                              pair_e, plo, W3eff);
    c34_kernel<<<dim3(32, 1, np), 256, 0, stream>>>(W3eff, b3eff, W4eff, b4eff,
                                                    y_T, featT, pair_e, plo, x1_T, g5_T);
    conv5_kernel<<<dim3(32, 1, ns), 256, 0, stream>>>(W5eff, b5tot, g5_T, x1_T,
                                                      gate_w, plo, out);
  }
}